// Round 12
// baseline (1122.614 us; speedup 1.0000x reference)
//
#include <hip/hip_runtime.h>
#include <hip/hip_cooperative_groups.h>
namespace cg = cooperative_groups;

#define B_    16
#define LBL_  48
#define PRED_ 336
#define CIN_  7
#define L_    384
#define DM_   512
#define E_    2
#define DIN_  1024
#define N_    16
#define DCONV_ 4
#define DTR_  32
#define TF_   4
#define EPSF  1e-5f
#define NSEG  8
#define SEGL  48
#define SC4   4
#define NCHK  12

typedef unsigned short u16;
typedef __attribute__((ext_vector_type(8))) short short8;
typedef __attribute__((ext_vector_type(4))) float f32x4;

__device__ __forceinline__ float bf2f(u16 u){
  union { float f; unsigned int i; } cv; cv.i = ((unsigned int)u) << 16; return cv.f;
}
__device__ __forceinline__ u16 f2bf(float f){
  union { float f; unsigned int i; } cv; cv.f = f;
  unsigned int x = cv.i;
  unsigned int lsb = (x >> 16) & 1u;
  x += 0x7fffu + lsb;
  return (u16)(x >> 16);
}
__device__ __forceinline__ float lo16(unsigned int v){
  union { float f; unsigned int i; } cv; cv.i = v << 16; return cv.f;
}
__device__ __forceinline__ float hi16(unsigned int v){
  union { float f; unsigned int i; } cv; cv.i = v & 0xffff0000u; return cv.f;
}

#define GLDS(g, l) __builtin_amdgcn_global_load_lds( \
    (const __attribute__((address_space(1))) void*)(g), \
    (__attribute__((address_space(3))) void*)(l), 16, 0, 0)

// ---- fp32 parameter block offsets inside d_ws (floats) ----
#define PO_XDEC   0
#define PO_XMARK  43008
#define PO_TOKW   67584
#define PO_TIMEF  78336
#define PO_NORMW  80384
#define PO_NORMB  81408
#define PO_INW    82432
#define PO_CONVW  2179584
#define PO_CONVB  2187776
#define PO_XPROJ  2189824
#define PO_DTW    2320896
#define PO_DTB    2386432
#define PO_ALOG   2388480
#define PO_DP     2421248
#define PO_OUTW   2423296
#define PO_FNW    3471872
#define PO_FNB    3472384
#define PO_HEADW  3472896
#define P_TOTAL   3476480
// ---- activation offsets (floats) ----
#define A_X    3476480
#define A_LNB  6622208
#define A_XZ   9767936
#define A_DT   22350848
#define A_DBC  28642304
#define A_XD   29035520
#define A_MEAN 29078528
#define A_STD  29078640

struct Ptrs { const void* p[18]; };
struct MArgs { Ptrs ps; float* P; void* out; };

// ===================== shared device helpers =====================

__device__ __forceinline__ void qpowers(float q, float* p){
  float q2 = q*q;
  float q4 = q2*q2;
  float q8 = q4*q4;
  float q3 = q2*q;
  p[0]=q;      p[1]=q2;     p[2]=q3;     p[3]=q4;
  p[4]=q4*q;   p[5]=q4*q2;  p[6]=q4*q3;  p[7]=q8;
  p[8]=q8*q;   p[9]=q8*q2;  p[10]=q8*q3; p[11]=q8*q4;
  p[12]=q8*p[4]; p[13]=q8*p[5]; p[14]=q8*p[6]; p[15]=q8*q8;
}

__device__ __forceinline__ float wredsum(float s){
  #pragma unroll
  for (int off = 32; off; off >>= 1) s += __shfl_xor(s, off, 64);
  return s;
}

// ===================== megakernel stages =====================

__device__ void mg_convert(const Ptrs& ps, float* dst){
  const int offs[18] = {PO_XDEC, PO_XMARK, PO_TOKW, PO_TIMEF, PO_NORMW, PO_NORMB,
                        PO_INW, PO_CONVW, PO_CONVB, PO_XPROJ, PO_DTW, PO_DTB,
                        PO_ALOG, PO_DP, PO_OUTW, PO_FNW, PO_FNB, PO_HEADW};
  int isbf = (((const u16*)ps.p[4])[0] == 0x3F80u);
  for (int idx = blockIdx.x*512 + threadIdx.x; idx < P_TOTAL; idx += 256*512){
    int seg = 0;
    #pragma unroll
    for (int s = 1; s < 18; s++) if (idx >= offs[s]) seg = s;
    int off = idx - offs[seg];
    if (seg == 6 || seg == 9 || seg == 14){
      u16 hv = isbf ? ((const u16*)ps.p[seg])[off]
                    : f2bf(((const float*)ps.p[seg])[off]);
      ((u16*)(dst + offs[seg]))[off] = hv;
    } else {
      float v = isbf ? bf2f(((const u16*)ps.p[seg])[off])
                     : ((const float*)ps.p[seg])[off];
      dst[idx] = v;
    }
  }
}

__device__ void mg_prep(const float* x_dec, float* xd, float* meanv, float* stdv){
  int wav = blockIdx.x*8 + (threadIdx.x >> 6);
  int lane = threadIdx.x & 63;
  if (wav >= B_*CIN_) return;
  int b = wav / CIN_, c = wav % CIN_;
  float v0 = (lane < LBL_) ? x_dec[(b*L_+lane)*CIN_+c] : 0.f;
  float m = wredsum(v0) * (1.f/LBL_);
  float dv = (lane < LBL_) ? (v0 - m) : 0.f;
  float sd = sqrtf(wredsum(dv*dv) * (1.f/LBL_) + EPSF);
  if (lane == 0){ meanv[wav] = m; stdv[wav] = sd; }
  float inv = 1.f / sd;
  #pragma unroll
  for (int t = lane; t < L_; t += 64){
    float v = x_dec[(b*L_+t)*CIN_+c];
    xd[(b*L_+t)*CIN_+c] = (t < LBL_) ? (v - m) * inv : v;
  }
}

__device__ void mg_embed(const float* xd, const float* token_w, const float* x_mark,
                         const float* timef_w, float* x){
  for (int idx = blockIdx.x*512 + threadIdx.x; idx < B_*L_*DM_; idx += 256*512){
    int d = idx & (DM_-1);
    int t = (idx >> 9) % L_;
    int b = idx / (DM_ * L_);
    int tm1 = (t == 0) ? L_-1 : t-1;
    int tp1 = (t == L_-1) ? 0 : t+1;
    const float* r0 = xd + (b*L_+tm1)*CIN_;
    const float* r1 = xd + (b*L_+t  )*CIN_;
    const float* r2 = xd + (b*L_+tp1)*CIN_;
    float acc = 0.f;
    #pragma unroll
    for (int ci = 0; ci < CIN_; ci++){
      const float* w = token_w + (d*CIN_+ci)*3;
      acc += r0[ci]*w[0] + r1[ci]*w[1] + r2[ci]*w[2];
    }
    #pragma unroll
    for (int f = 0; f < TF_; f++)
      acc += x_mark[(b*L_+t)*TF_+f] * timef_w[d*TF_+f];
    x[idx] = acc;
  }
}

// wave-per-token LN -> bf16
__device__ void mg_ln(const float* x, const float* w, const float* bias, u16* out){
  int wav = blockIdx.x*8 + (threadIdx.x >> 6);
  int lane = threadIdx.x & 63;
  for (int tok = wav; tok < B_*L_; tok += 2048){
    const float* xr = x + (size_t)tok*DM_ + lane*8;
    float4 a = *(const float4*)xr;
    float4 bq = *(const float4*)(xr + 4);
    float v[8] = {a.x,a.y,a.z,a.w,bq.x,bq.y,bq.z,bq.w};
    float s = (v[0]+v[1])+(v[2]+v[3])+((v[4]+v[5])+(v[6]+v[7]));
    float mean = wredsum(s) * (1.f/DM_);
    float s2 = 0.f;
    #pragma unroll
    for (int j = 0; j < 8; j++){ v[j] -= mean; s2 += v[j]*v[j]; }
    float rstd = rsqrtf(wredsum(s2) * (1.f/DM_) + EPSF);
    const float* wr = w + lane*8;
    const float* br = bias + lane*8;
    uint4 o; unsigned int* op = (unsigned int*)&o;
    #pragma unroll
    for (int k = 0; k < 4; k++){
      u16 e0 = f2bf(v[2*k]   * rstd * wr[2*k]   + br[2*k]);
      u16 e1 = f2bf(v[2*k+1] * rstd * wr[2*k+1] + br[2*k+1]);
      op[k] = (unsigned int)e0 | ((unsigned int)e1 << 16);
    }
    *(uint4*)(out + (size_t)tok*DM_ + lane*8) = o;
  }
}

// virtual-block MFMA GEMM (2 x 256-thread vblocks per real block)
template<int TN, int ACCUM, int BF16OUT>
__device__ void mg_gemm(float* smemf, const u16* __restrict__ A, const u16* __restrict__ Wt,
                        void* __restrict__ C, int M, int N, int K){
  constexpr int WN = TN / 2;
  constexpr int NI = WN / 16;
  int half = threadIdx.x >> 8;
  int tid  = threadIdx.x & 255;
  u16* As = (u16*)smemf + half * (128*32 + TN*32);
  u16* Ws = As + 128*32;
  int wv = tid >> 6, lane = tid & 63;
  int wm = (wv & 1) * 64, wn = (wv >> 1) * WN;
  int la = lane & 15, lk = lane >> 4;
  int srow = lane >> 2, scol = (lane & 3) * 8;
  int mb = M / 128;
  int numVB = mb * (N / TN);          // always even here
  for (int vb0 = blockIdx.x*2; vb0 < numVB; vb0 += 512){
    int vb = vb0 + half;
    int by = vb % mb, bx = vb / mb;
    int m0 = by*128, n0 = bx*TN;
    f32x4 acc[4][NI];
    #pragma unroll
    for (int i = 0; i < 4; i++)
      #pragma unroll
      for (int j = 0; j < NI; j++) acc[i][j] = (f32x4){0.f,0.f,0.f,0.f};
    const u16* Ag0 = A + (size_t)(m0 + wv*32 + srow) * K + scol;
    const u16* Ag1 = Ag0 + (size_t)16 * K;
    u16* Al0 = As + wv*1024 + lane*8;
    u16* Al1 = Al0 + 512;
    const u16 *Wg0, *Wg1; u16 *Wl0, *Wl1;
    if constexpr (TN == 128){
      Wg0 = Wt + (size_t)(n0 + wv*32 + srow) * K + scol;
      Wg1 = Wg0 + (size_t)16 * K;
      Wl0 = Ws + wv*1024 + lane*8;
      Wl1 = Wl0 + 512;
    } else {
      Wg0 = Wt + (size_t)(n0 + wv*16 + srow) * K + scol;
      Wg1 = nullptr;
      Wl0 = Ws + wv*512 + lane*8;
      Wl1 = nullptr;
    }
    for (int k0 = 0; k0 < K; k0 += 32){
      GLDS(Ag0 + k0, Al0);
      GLDS(Ag1 + k0, Al1);
      GLDS(Wg0 + k0, Wl0);
      if constexpr (TN == 128) GLDS(Wg1 + k0, Wl1);
      __syncthreads();
      short8 af[4], bfr[NI];
      #pragma unroll
      for (int mi = 0; mi < 4; mi++) af[mi] = *(const short8*)&As[(wm + mi*16 + la)*32 + lk*8];
      #pragma unroll
      for (int ni = 0; ni < NI; ni++) bfr[ni] = *(const short8*)&Ws[(wn + ni*16 + la)*32 + lk*8];
      #pragma unroll
      for (int mi = 0; mi < 4; mi++)
        #pragma unroll
        for (int ni = 0; ni < NI; ni++)
          acc[mi][ni] = __builtin_amdgcn_mfma_f32_16x16x32_bf16(af[mi], bfr[ni], acc[mi][ni], 0, 0, 0);
      __syncthreads();
    }
    #pragma unroll
    for (int mi = 0; mi < 4; mi++)
      #pragma unroll
      for (int ni = 0; ni < NI; ni++){
        int row = m0 + wm + mi*16 + lk*4;
        int col = n0 + wn + ni*16 + la;
        #pragma unroll
        for (int r = 0; r < 4; r++){
          if constexpr (BF16OUT){
            u16* p = (u16*)C + (size_t)row * N + col;
            p[(size_t)r * N] = f2bf(acc[mi][ni][r]);
          } else {
            float* p = (float*)C + (size_t)row * N + col;
            if (ACCUM) p[(size_t)r * N] += acc[mi][ni][r];
            else       p[(size_t)r * N]  = acc[mi][ni][r];
          }
        }
      }
  }
}

__device__ void mg_conv(const u16* xz, const float* cw, const float* cb, u16* xcb){
  for (int e = blockIdx.x*512 + threadIdx.x; e < B_*L_*DIN_/8; e += 256*512){
    int c8 = (e & (DIN_/8 - 1)) * 8;
    int bt = e >> 7;
    int t  = bt % L_;
    const u16* base = xz + (size_t)bt * (2*DIN_) + c8;
    uint4 tap[4];
    tap[3] = *(const uint4*)base;
    if (t >= 1) tap[2] = *(const uint4*)(base - 1*2*DIN_);
    if (t >= 2) tap[1] = *(const uint4*)(base - 2*2*DIN_);
    if (t >= 3) tap[0] = *(const uint4*)(base - 3*2*DIN_);
    float v[8];
    #pragma unroll
    for (int k = 0; k < 8; k++){
      float4 w = *(const float4*)(cw + (c8 + k)*4);
      float s = cb[c8 + k];
      #pragma unroll
      for (int j = 0; j < 4; j++){
        if (j >= 3 - t){
          const unsigned int* tp = (const unsigned int*)&tap[j];
          float xv = (k & 1) ? hi16(tp[k >> 1]) : lo16(tp[k >> 1]);
          s += xv * ((const float*)&w)[j];
        }
      }
      v[k] = s / (1.f + __expf(-s));
    }
    uint4 o; unsigned int* op = (unsigned int*)&o;
    #pragma unroll
    for (int k = 0; k < 4; k++)
      op[k] = (unsigned int)f2bf(v[2*k]) | ((unsigned int)f2bf(v[2*k+1]) << 16);
    *(uint4*)(xcb + (size_t)bt * DIN_ + c8) = o;
  }
}

__device__ void mg_dtproj(float* smemf, const float* dbc, const float* dtw,
                          const float* dtb, u16* dt){
  int half = threadIdx.x >> 8;
  int tid  = threadIdx.x & 255;
  float* r = smemf + half * 1056;     // [32][33]
  const int numVB = 4 * 192;          // even
  for (int vb0 = blockIdx.x*2; vb0 < numVB; vb0 += 512){
    int vb = vb0 + half;
    int dblk = vb & 3, tblk = vb >> 2;
    int tok0 = tblk * 32;
    int d = dblk*256 + tid;
    {
      int t = tid >> 3, col = (tid & 7) * 4;
      *(float4*)&r[t*33 + col] = *(const float4*)(dbc + (size_t)(tok0 + t)*64 + col);
    }
    __syncthreads();
    float w[32];
    #pragma unroll
    for (int k = 0; k < 32; k += 4){
      float4 wv = *(const float4*)(dtw + (size_t)d*DTR_ + k);
      w[k] = wv.x; w[k+1] = wv.y; w[k+2] = wv.z; w[k+3] = wv.w;
    }
    float bias = dtb[d];
    for (int t = 0; t < 32; t++){
      float acc = bias;
      #pragma unroll
      for (int k = 0; k < 32; k++) acc += w[k] * r[t*33 + k];
      float sp = (acc > 20.f) ? acc : log1pf(__expf(acc));
      dt[(size_t)(tok0 + t) * DIN_ + d] = f2bf(sp);
    }
    __syncthreads();
  }
}

#define WST4 1792
__device__ void mg_scan(float* smem, u16* ub_yb, const float* dbc, const u16* xz,
                        const u16* dtp, const float* A_log, const float* Dp){
  int tid = threadIdx.x;
  int lane = tid & 63;
  int seg  = tid >> 6;
  int b = blockIdx.x >> 4;
  int g = blockIdx.x & 15;
  int d = g*64 + lane;
  size_t base = (size_t)b * L_;

  float* wbase = smem + seg * WST4;
  float* sbc = wbase;
  float* su  = wbase + 256;
  float* sz  = wbase + 768;
  float* sdt = wbase + 1280;

  int st  = lane >> 4;
  int c16 = lane & 15;

  float A[16];
  #pragma unroll
  for (int n = 0; n < 16; n += 4){
    float4 av = *(const float4*)(A_log + (size_t)d*N_ + n);
    A[n] = -__expf(av.x); A[n+1] = -__expf(av.y); A[n+2] = -__expf(av.z); A[n+3] = -__expf(av.w);
  }
  float Dv = Dp[d];
  bool fastA = true;
  #pragma unroll
  for (int n = 0; n < 16; n++) fastA = fastA && (fabsf(A[n] + (float)(n+1)) < 1e-3f*(n+1));

  float h[16];
  #pragma unroll
  for (int n = 0; n < 16; n++) h[n] = 0.f;

  auto ldc = [&](int c, float2& kbc, uint2& ku, uint2& kz, uint2& kt, bool wz){
    size_t tokr = base + seg*SEGL + c*SC4 + st;
    kbc = *(const float2*)(dbc + tokr*64 + 32 + c16*2);
    ku  = *(const uint2*)(ub_yb + tokr*DIN_ + g*64 + c16*4);
    kt  = *(const uint2*)(dtp + tokr*DIN_ + g*64 + c16*4);
    if (wz) kz = *(const uint2*)(xz + tokr*(2*DIN_) + DIN_ + g*64 + c16*4);
  };
  auto cvt4 = [&](const uint2& v, float* dst){
    dst[0] = lo16(v.x); dst[1] = hi16(v.x);
    dst[2] = lo16(v.y); dst[3] = hi16(v.y);
  };
  auto stc = [&](int buf, const float2& kbc, const uint2& ku, const uint2& kz,
                 const uint2& kt, bool wz){
    *(float2*)&sbc[buf*128 + st*32 + c16*2] = kbc;
    cvt4(ku, &su[buf*256 + st*64 + c16*4]);
    cvt4(kt, &sdt[buf*256 + st*64 + c16*4]);
    if (wz) cvt4(kz, &sz[buf*256 + st*64 + c16*4]);
  };

  float S = 0.f;
  {
    float2 kbc; uint2 ku, kz, kt;
    ldc(0, kbc, ku, kz, kt, false);
    stc(0, kbc, ku, kz, kt, false);
    for (int c = 0; c < NCHK; c++){
      int cur = c & 1;
      bool have = (c + 1 < NCHK);
      float2 nbc; uint2 nu, nz, nt;
      if (have) ldc(c+1, nbc, nu, nz, nt, false);
      for (int s = 0; s < SC4; s++){
        float dtv = sdt[cur*256 + s*64 + lane];
        float u   = su [cur*256 + s*64 + lane];
        const float* bcrow = sbc + cur*128 + s*32;
        float Bf[16];
        #pragma unroll
        for (int i = 0; i < 16; i += 4){
          float4 bv = *(const float4*)(bcrow + i);
          Bf[i] = bv.x; Bf[i+1] = bv.y; Bf[i+2] = bv.z; Bf[i+3] = bv.w;
        }
        float du = dtv * u;
        S += dtv;
        if (fastA){
          float q = __expf(-dtv);
          float p[16];
          qpowers(q, p);
          #pragma unroll
          for (int n = 0; n < 16; n++) h[n] = p[n] * h[n] + du * Bf[n];
        } else {
          #pragma unroll
          for (int n = 0; n < 16; n++){
            float dA = __expf(dtv * A[n]);
            h[n] = dA * h[n] + du * Bf[n];
          }
        }
      }
      if (have) stc(1 - cur, nbc, nu, nz, nt, false);
    }
  }

  __syncthreads();
  #pragma unroll
  for (int n = 0; n < 16; n++){
    smem[(n*NSEG + seg)*64 + lane]        = h[n];
    smem[8192 + (n*NSEG + seg)*64 + lane] = __expf(A[n] * S);
  }
  __syncthreads();
  {
    float hs[16];
    #pragma unroll
    for (int n = 0; n < 16; n++) hs[n] = 0.f;
    for (int j = 0; j < seg; j++){
      #pragma unroll
      for (int n = 0; n < 16; n++){
        float qh = smem[(n*NSEG + j)*64 + lane];
        float qP = smem[8192 + (n*NSEG + j)*64 + lane];
        hs[n] = qh + qP * hs[n];
      }
    }
    #pragma unroll
    for (int n = 0; n < 16; n++) h[n] = hs[n];
  }
  __syncthreads();

  {
    float2 kbc; uint2 ku, kz, kt;
    ldc(0, kbc, ku, kz, kt, true);
    stc(0, kbc, ku, kz, kt, true);
    for (int c = 0; c < NCHK; c++){
      int cur = c & 1;
      bool have = (c + 1 < NCHK);
      float2 nbc; uint2 nu, nz, nt;
      if (have) ldc(c+1, nbc, nu, nz, nt, true);
      for (int s = 0; s < SC4; s++){
        float dtv = sdt[cur*256 + s*64 + lane];
        float u   = su [cur*256 + s*64 + lane];
        float z   = sz [cur*256 + s*64 + lane];
        const float* bcrow = sbc + cur*128 + s*32;
        float Bf[16], Cf[16];
        #pragma unroll
        for (int i = 0; i < 16; i += 4){
          float4 bv = *(const float4*)(bcrow + i);
          float4 cv = *(const float4*)(bcrow + 16 + i);
          Bf[i] = bv.x; Bf[i+1] = bv.y; Bf[i+2] = bv.z; Bf[i+3] = bv.w;
          Cf[i] = cv.x; Cf[i+1] = cv.y; Cf[i+2] = cv.z; Cf[i+3] = cv.w;
        }
        float du = dtv * u;
        float acc = 0.f;
        if (fastA){
          float q = __expf(-dtv);
          float p[16];
          qpowers(q, p);
          #pragma unroll
          for (int n = 0; n < 16; n++){
            h[n] = p[n] * h[n] + du * Bf[n];
            acc += h[n] * Cf[n];
          }
        } else {
          #pragma unroll
          for (int n = 0; n < 16; n++){
            float dA = __expf(dtv * A[n]);
            h[n] = dA * h[n] + du * Bf[n];
            acc += h[n] * Cf[n];
          }
        }
        float y = acc + u * Dv;
        size_t tok = base + seg*SEGL + c*SC4 + s;
        ub_yb[tok*DIN_ + d] = f2bf(y * (z / (1.f + __expf(-z))));
      }
      if (have) stc(1 - cur, nbc, nu, nz, nt, true);
    }
  }
}

__device__ void mg_head(const float* x, const float* fw, const float* fb, const float* ow,
                        const float* meanv, const float* stdv, void* out, int isbf){
  int wav = blockIdx.x*8 + (threadIdx.x >> 6);
  int lane = threadIdx.x & 63;
  for (int tk = wav; tk < B_*PRED_; tk += 2048){
    int b = tk / PRED_;
    int tt = tk % PRED_;
    int tok = b*L_ + LBL_ + tt;
    const float* xr = x + (size_t)tok*DM_ + lane*8;
    float4 a = *(const float4*)xr;
    float4 bq = *(const float4*)(xr + 4);
    float v[8] = {a.x,a.y,a.z,a.w,bq.x,bq.y,bq.z,bq.w};
    float s = (v[0]+v[1])+(v[2]+v[3])+((v[4]+v[5])+(v[6]+v[7]));
    float mean = wredsum(s) * (1.f/DM_);
    float s2 = 0.f;
    #pragma unroll
    for (int j = 0; j < 8; j++){ v[j] -= mean; s2 += v[j]*v[j]; }
    float rstd = rsqrtf(wredsum(s2) * (1.f/DM_) + EPSF);
    const float* fwr = fw + lane*8;
    const float* fbr = fb + lane*8;
    #pragma unroll
    for (int j = 0; j < 8; j++) v[j] = v[j] * rstd * fwr[j] + fbr[j];
    for (int o = 0; o < CIN_; o++){
      const float* owr = ow + (size_t)o*DM_ + lane*8;
      float part = 0.f;
      #pragma unroll
      for (int j = 0; j < 8; j++) part += v[j] * owr[j];
      part = wredsum(part);
      if (lane == 0){
        float res = part * stdv[b*CIN_ + o] + meanv[b*CIN_ + o];
        size_t oidx = (size_t)(b*PRED_ + tt)*CIN_ + o;
        if (isbf) ((u16*)out)[oidx] = f2bf(res);
        else      ((float*)out)[oidx] = res;
      }
    }
  }
}

// ===================== the megakernel =====================

__global__ void __launch_bounds__(512, 1) mega_kernel(MArgs a){
  cg::grid_group grid = cg::this_grid();
  __shared__ float smem[16384];   // 64 KB, reused per stage
  float* P = a.P;
  float* x    = P + A_X;
  u16*   lnxb = (u16*)(P + A_LNB);
  u16*   xcb  = (u16*)(P + A_LNB);
  u16*   xz   = (u16*)(P + A_XZ);
  u16*   dt   = (u16*)(P + A_DT);
  float* dbc  = P + A_DBC;
  float* xd   = P + A_XD;
  float* meanv= P + A_MEAN;
  float* stdv = P + A_STD;
  const u16* bwi = (const u16*)(P + PO_INW);
  const u16* bwx = (const u16*)(P + PO_XPROJ);
  const u16* bwo = (const u16*)(P + PO_OUTW);
  int isbf = (((const u16*)a.ps.p[4])[0] == 0x3F80u);

  mg_convert(a.ps, P);
  grid.sync();
  mg_prep(P + PO_XDEC, xd, meanv, stdv);
  grid.sync();
  mg_embed(xd, P + PO_TOKW, P + PO_XMARK, P + PO_TIMEF, x);
  grid.sync();

  for (int e = 0; e < E_; e++){
    mg_ln(x, P + PO_NORMW + e*DM_, P + PO_NORMB + e*DM_, lnxb);
    grid.sync();
    mg_gemm<128,0,1>(smem, lnxb, bwi + (size_t)e*2*DIN_*DM_, xz, B_*L_, 2*DIN_, DM_);
    grid.sync();
    mg_conv(xz, P + PO_CONVW + e*DIN_*DCONV_, P + PO_CONVB + e*DIN_, xcb);
    grid.sync();
    mg_gemm<64,0,0>(smem, xcb, bwx + (size_t)e*64*DIN_, dbc, B_*L_, 64, DIN_);
    grid.sync();
    mg_dtproj(smem, dbc, P + PO_DTW + e*DIN_*DTR_, P + PO_DTB + e*DIN_, dt);
    grid.sync();
    mg_scan(smem, xcb, dbc, xz, dt, P + PO_ALOG + e*DIN_*N_, P + PO_DP + e*DIN_);
    grid.sync();
    mg_gemm<64,1,0>(smem, xcb, bwo + (size_t)e*DM_*DIN_, x, B_*L_, DM_, DIN_);
    grid.sync();
  }

  mg_head(x, P + PO_FNW, P + PO_FNB, P + PO_HEADW, meanv, stdv, a.out, isbf);
}

// ===================== fallback multi-kernel path (round-11, proven) =====================

__global__ __launch_bounds__(256) void convert_kernel(Ptrs ps, float* __restrict__ dst){
  const int offs[18] = {PO_XDEC, PO_XMARK, PO_TOKW, PO_TIMEF, PO_NORMW, PO_NORMB,
                        PO_INW, PO_CONVW, PO_CONVB, PO_XPROJ, PO_DTW, PO_DTB,
                        PO_ALOG, PO_DP, PO_OUTW, PO_FNW, PO_FNB, PO_HEADW};
  int idx = blockIdx.x * 256 + threadIdx.x;
  if (idx >= P_TOTAL) return;
  int seg = 0;
  #pragma unroll
  for (int s = 1; s < 18; s++) if (idx >= offs[s]) seg = s;
  int off = idx - offs[seg];
  int isbf = (((const u16*)ps.p[4])[0] == 0x3F80u);
  if (seg == 6 || seg == 9 || seg == 14){
    u16 hv = isbf ? ((const u16*)ps.p[seg])[off]
                  : f2bf(((const float*)ps.p[seg])[off]);
    ((u16*)(dst + offs[seg]))[off] = hv;
  } else {
    float v = isbf ? bf2f(((const u16*)ps.p[seg])[off])
                   : ((const float*)ps.p[seg])[off];
    dst[idx] = v;
  }
}

__global__ __launch_bounds__(64) void prep_kernel(const float* __restrict__ x_dec, float* __restrict__ xd,
                            float* __restrict__ meanv, float* __restrict__ stdv){
  int i = blockIdx.x;
  int b = i / CIN_, c = i % CIN_;
  int lane = threadIdx.x;
  float v0 = (lane < LBL_) ? x_dec[(b*L_+lane)*CIN_+c] : 0.f;
  float m = wredsum(v0) * (1.f/LBL_);
  float dv = (lane < LBL_) ? (v0 - m) : 0.f;
  float sd = sqrtf(wredsum(dv*dv) * (1.f/LBL_) + EPSF);
  if (lane == 0){ meanv[i] = m; stdv[i] = sd; }
  float inv = 1.f / sd;
  #pragma unroll
  for (int t = lane; t < L_; t += 64){
    float v = x_dec[(b*L_+t)*CIN_+c];
    xd[(b*L_+t)*CIN_+c] = (t < LBL_) ? (v - m) * inv : v;
  }
}

__global__ __launch_bounds__(256) void embed_kernel(const float* __restrict__ xd,
      const float* __restrict__ token_w, const float* __restrict__ x_mark,
      const float* __restrict__ timef_w, float* __restrict__ x){
  int idx = blockIdx.x * 256 + threadIdx.x;
  int d = idx & (DM_-1);
  int t = (idx >> 9) % L_;
  int b = idx / (DM_ * L_);
  int tm1 = (t == 0) ? L_-1 : t-1;
  int tp1 = (t == L_-1) ? 0 : t+1;
  const float* r0 = xd + (b*L_+tm1)*CIN_;
  const float* r1 = xd + (b*L_+t  )*CIN_;
  const float* r2 = xd + (b*L_+tp1)*CIN_;
  float acc = 0.f;
  #pragma unroll
  for (int ci = 0; ci < CIN_; ci++){
    const float* w = token_w + (d*CIN_+ci)*3;
    acc += r0[ci]*w[0] + r1[ci]*w[1] + r2[ci]*w[2];
  }
  #pragma unroll
  for (int f = 0; f < TF_; f++)
    acc += x_mark[(b*L_+t)*TF_+f] * timef_w[d*TF_+f];
  x[idx] = acc;
}

__global__ __launch_bounds__(256) void ln_kernel(const float* __restrict__ x,
     const float* __restrict__ w, const float* __restrict__ bias, u16* __restrict__ out){
  int wav = blockIdx.x*4 + (threadIdx.x >> 6);
  int lane = threadIdx.x & 63;
  int tok = wav;
  if (tok >= B_*L_) return;
  const float* xr = x + (size_t)tok*DM_ + lane*8;
  float4 a = *(const float4*)xr;
  float4 bq = *(const float4*)(xr + 4);
  float v[8] = {a.x,a.y,a.z,a.w,bq.x,bq.y,bq.z,bq.w};
  float s = (v[0]+v[1])+(v[2]+v[3])+((v[4]+v[5])+(v[6]+v[7]));
  float mean = wredsum(s) * (1.f/DM_);
  float s2 = 0.f;
  #pragma unroll
  for (int j = 0; j < 8; j++){ v[j] -= mean; s2 += v[j]*v[j]; }
  float rstd = rsqrtf(wredsum(s2) * (1.f/DM_) + EPSF);
  const float* wr = w + lane*8;
  const float* br = bias + lane*8;
  uint4 o; unsigned int* op = (unsigned int*)&o;
  #pragma unroll
  for (int k = 0; k < 4; k++){
    u16 e0 = f2bf(v[2*k]   * rstd * wr[2*k]   + br[2*k]);
    u16 e1 = f2bf(v[2*k+1] * rstd * wr[2*k+1] + br[2*k+1]);
    op[k] = (unsigned int)e0 | ((unsigned int)e1 << 16);
  }
  *(uint4*)(out + (size_t)tok*DM_ + lane*8) = o;
}

template<int TN, int ACCUM, int BF16OUT>
__global__ __launch_bounds__(256) void gemm_mfma(const u16* __restrict__ A, const u16* __restrict__ Wt,
    void* __restrict__ C, int M, int N, int K){
  constexpr int WN = TN / 2;
  constexpr int NI = WN / 16;
  __shared__ u16 As[128 * 32];
  __shared__ u16 Ws[TN * 32];
  int tid = threadIdx.x;
  int wv = tid >> 6, lane = tid & 63;
  int wm = (wv & 1) * 64, wn = (wv >> 1) * WN;
  int m0 = blockIdx.y * 128, n0 = blockIdx.x * TN;
  int la = lane & 15, lk = lane >> 4;
  f32x4 acc[4][NI];
  #pragma unroll
  for (int i = 0; i < 4; i++)
    #pragma unroll
    for (int j = 0; j < NI; j++) acc[i][j] = (f32x4){0.f, 0.f, 0.f, 0.f};
  int srow = lane >> 2, scol = (lane & 3) * 8;
  const u16* Ag0 = A + (size_t)(m0 + wv*32 + srow) * K + scol;
  const u16* Ag1 = Ag0 + (size_t)16 * K;
  u16* Al0 = As + wv*1024 + lane*8;
  u16* Al1 = As + wv*1024 + 512 + lane*8;
  const u16 *Wg0, *Wg1;
  u16 *Wl0, *Wl1;
  if constexpr (TN == 128){
    Wg0 = Wt + (size_t)(n0 + wv*32 + srow) * K + scol;
    Wg1 = Wg0 + (size_t)16 * K;
    Wl0 = Ws + wv*1024 + lane*8;
    Wl1 = Ws + wv*1024 + 512 + lane*8;
  } else {
    Wg0 = Wt + (size_t)(n0 + wv*16 + srow) * K + scol;
    Wg1 = nullptr;
    Wl0 = Ws + wv*512 + lane*8;
    Wl1 = nullptr;
  }
  for (int k0 = 0; k0 < K; k0 += 32){
    GLDS(Ag0 + k0, Al0);
    GLDS(Ag1 + k0, Al1);
    GLDS(Wg0 + k0, Wl0);
    if constexpr (TN == 128) GLDS(Wg1 + k0, Wl1);
    __syncthreads();
    short8 af[4], bfr[NI];
    #pragma unroll
    for (int mi = 0; mi < 4; mi++) af[mi] = *(const short8*)&As[(wm + mi*16 + la)*32 + lk*8];
    #pragma unroll
    for (int ni = 0; ni < NI; ni++) bfr[ni] = *(const short8*)&Ws[(wn + ni*16 + la)*32 + lk*8];
    #pragma unroll
    for (int mi = 0; mi < 4; mi++)
      #pragma unroll
      for (int ni = 0; ni < NI; ni++)
        acc[mi][ni] = __builtin_amdgcn_mfma_f32_16x16x32_bf16(af[mi], bfr[ni], acc[mi][ni], 0, 0, 0);
    __syncthreads();
  }
  #pragma unroll
  for (int mi = 0; mi < 4; mi++)
    #pragma unroll
    for (int ni = 0; ni < NI; ni++){
      int row = m0 + wm + mi*16 + lk*4;
      int col = n0 + wn + ni*16 + la;
      #pragma unroll
      for (int r = 0; r < 4; r++){
        if constexpr (BF16OUT){
          u16* p = (u16*)C + (size_t)row * N + col;
          p[(size_t)r * N] = f2bf(acc[mi][ni][r]);
        } else {
          float* p = (float*)C + (size_t)row * N + col;
          if (ACCUM) p[(size_t)r * N] += acc[mi][ni][r];
          else       p[(size_t)r * N]  = acc[mi][ni][r];
        }
      }
    }
}

__global__ __launch_bounds__(256) void conv_silu_kernel(const u16* __restrict__ xz,
   const float* __restrict__ cw, const float* __restrict__ cb, u16* __restrict__ xcb){
  int e = blockIdx.x * 256 + threadIdx.x;
  int c8 = (e & (DIN_/8 - 1)) * 8;
  int bt = e >> 7;
  int t  = bt % L_;
  const u16* base = xz + (size_t)bt * (2*DIN_) + c8;
  uint4 tap[4];
  tap[3] = *(const uint4*)base;
  if (t >= 1) tap[2] = *(const uint4*)(base - 1*2*DIN_);
  if (t >= 2) tap[1] = *(const uint4*)(base - 2*2*DIN_);
  if (t >= 3) tap[0] = *(const uint4*)(base - 3*2*DIN_);
  float v[8];
  #pragma unroll
  for (int k = 0; k < 8; k++){
    float4 w = *(const float4*)(cw + (c8 + k)*4);
    float s = cb[c8 + k];
    #pragma unroll
    for (int j = 0; j < 4; j++){
      if (j >= 3 - t){
        const unsigned int* tp = (const unsigned int*)&tap[j];
        float xv = (k & 1) ? hi16(tp[k >> 1]) : lo16(tp[k >> 1]);
        s += xv * ((const float*)&w)[j];
      }
    }
    v[k] = s / (1.f + __expf(-s));
  }
  uint4 o;
  unsigned int* op = (unsigned int*)&o;
  #pragma unroll
  for (int k = 0; k < 4; k++)
    op[k] = (unsigned int)f2bf(v[2*k]) | ((unsigned int)f2bf(v[2*k+1]) << 16);
  *(uint4*)(xcb + (size_t)bt * DIN_ + c8) = o;
}

__global__ __launch_bounds__(256) void dtproj_kernel(const float* __restrict__ dbc,
    const float* __restrict__ dtw, const float* __restrict__ dtb, u16* __restrict__ dt){
  __shared__ float r[32][33];
  int tid = threadIdx.x;
  int tok0 = blockIdx.y * 32;
  int d = blockIdx.x * 256 + tid;
  {
    int t = tid >> 3, col = (tid & 7) * 4;
    *(float4*)&r[t][col] = *(const float4*)(dbc + (size_t)(tok0 + t)*64 + col);
  }
  __syncthreads();
  float w[32];
  #pragma unroll
  for (int k = 0; k < 32; k += 4){
    float4 wv = *(const float4*)(dtw + (size_t)d*DTR_ + k);
    w[k] = wv.x; w[k+1] = wv.y; w[k+2] = wv.z; w[k+3] = wv.w;
  }
  float bias = dtb[d];
  for (int t = 0; t < 32; t++){
    float acc = bias;
    #pragma unroll
    for (int k = 0; k < 32; k++) acc += w[k] * r[t][k];
    float sp = (acc > 20.f) ? acc : log1pf(__expf(acc));
    dt[(size_t)(tok0 + t) * DIN_ + d] = f2bf(sp);
  }
}

__global__ __launch_bounds__(512, 1) void scan_kernel(
    u16* __restrict__ ub_yb,
    const float* __restrict__ dbc, const u16* __restrict__ xz,
    const u16* __restrict__ dtp,
    const float* __restrict__ A_log, const float* __restrict__ Dp){
  __shared__ float smem[16384];
  mg_scan(smem, ub_yb, dbc, xz, dtp, A_log, Dp);
}

__global__ __launch_bounds__(256) void head_kernel(const float* __restrict__ x,
    const float* __restrict__ fw, const float* __restrict__ fb, const float* __restrict__ ow,
    const float* __restrict__ meanv, const float* __restrict__ stdv, void* __restrict__ out,
    const u16* __restrict__ dtype_probe){
  int wav = blockIdx.x*4 + (threadIdx.x >> 6);
  int lane = threadIdx.x & 63;
  if (wav >= B_*PRED_) return;
  int b = wav / PRED_;
  int tt = wav % PRED_;
  int tok = b*L_ + LBL_ + tt;
  const float* xr = x + (size_t)tok*DM_ + lane*8;
  float4 a = *(const float4*)xr;
  float4 bq = *(const float4*)(xr + 4);
  float v[8] = {a.x,a.y,a.z,a.w,bq.x,bq.y,bq.z,bq.w};
  float s = (v[0]+v[1])+(v[2]+v[3])+((v[4]+v[5])+(v[6]+v[7]));
  float mean = wredsum(s) * (1.f/DM_);
  float s2 = 0.f;
  #pragma unroll
  for (int j = 0; j < 8; j++){ v[j] -= mean; s2 += v[j]*v[j]; }
  float rstd = rsqrtf(wredsum(s2) * (1.f/DM_) + EPSF);
  const float* fwr = fw + lane*8;
  const float* fbr = fb + lane*8;
  #pragma unroll
  for (int j = 0; j < 8; j++) v[j] = v[j] * rstd * fwr[j] + fbr[j];
  int isbf = (dtype_probe[0] == 0x3F80u);
  for (int o = 0; o < CIN_; o++){
    const float* owr = ow + (size_t)o*DM_ + lane*8;
    float part = 0.f;
    #pragma unroll
    for (int j = 0; j < 8; j++) part += v[j] * owr[j];
    part = wredsum(part);
    if (lane == 0){
      float res = part * stdv[b*CIN_ + o] + meanv[b*CIN_ + o];
      size_t oidx = (size_t)(b*PRED_ + tt)*CIN_ + o;
      if (isbf) ((u16*)out)[oidx] = f2bf(res);
      else      ((float*)out)[oidx] = res;
    }
  }
}

extern "C" void kernel_launch(void* const* d_in, const int* in_sizes, int n_in,
                              void* d_out, int out_size, void* d_ws, size_t ws_size,
                              hipStream_t stream){
  float* P = (float*)d_ws;

  Ptrs ps;
  for (int i = 0; i < 18; i++) ps.p[i] = d_in[2 + i];

  MArgs ma; ma.ps = ps; ma.P = P; ma.out = d_out;
  void* kargs[] = { &ma };
  hipError_t err = hipLaunchCooperativeKernel((void*)mega_kernel, dim3(256), dim3(512),
                                              kargs, 0, stream);
  if (err == hipSuccess) return;
  (void)hipGetLastError();   // clear error state, run fallback

  float* x    = P + A_X;
  u16*   lnxb = (u16*)(P + A_LNB);
  u16*   xcb  = (u16*)(P + A_LNB);
  u16*   xz   = (u16*)(P + A_XZ);
  u16*   dt   = (u16*)(P + A_DT);
  float* dbc  = P + A_DBC;
  float* xd   = P + A_XD;
  float* meanv= P + A_MEAN;
  float* stdv = P + A_STD;
  const u16* bwi = (const u16*)(P + PO_INW);
  const u16* bwx = (const u16*)(P + PO_XPROJ);
  const u16* bwo = (const u16*)(P + PO_OUTW);

  convert_kernel<<<(P_TOTAL+255)/256, 256, 0, stream>>>(ps, P);
  prep_kernel<<<B_*CIN_, 64, 0, stream>>>(P + PO_XDEC, xd, meanv, stdv);
  embed_kernel<<<(B_*L_*DM_)/256, 256, 0, stream>>>(
      xd, P + PO_TOKW, P + PO_XMARK, P + PO_TIMEF, x);

  for (int e = 0; e < E_; e++){
    ln_kernel<<<(B_*L_)/4, 256, 0, stream>>>(x, P + PO_NORMW + e*DM_, P + PO_NORMB + e*DM_, lnxb);
    gemm_mfma<128,0,1><<<dim3((2*DIN_)/128, (B_*L_)/128), 256, 0, stream>>>(
        lnxb, bwi + (size_t)e*2*DIN_*DM_, xz, B_*L_, 2*DIN_, DM_);
    conv_silu_kernel<<<(B_*L_*DIN_)/(256*8), 256, 0, stream>>>(
        xz, P + PO_CONVW + e*DIN_*DCONV_, P + PO_CONVB + e*DIN_, xcb);
    gemm_mfma<64,0,0><<<dim3(1, (B_*L_)/128), 256, 0, stream>>>(
        xcb, bwx + (size_t)e*64*DIN_, dbc, B_*L_, 64, DIN_);
    dtproj_kernel<<<dim3(DIN_/256, (B_*L_)/32), 256, 0, stream>>>(
        dbc, P + PO_DTW + e*DIN_*DTR_, P + PO_DTB + e*DIN_, dt);
    scan_kernel<<<256, 512, 0, stream>>>(
        xcb, dbc, xz, dt, P + PO_ALOG + e*DIN_*N_, P + PO_DP + e*DIN_);
    gemm_mfma<64,1,0><<<dim3(DM_/64, (B_*L_)/128), 256, 0, stream>>>(
        xcb, bwo + (size_t)e*DM_*DIN_, x, B_*L_, DM_, DIN_);
  }

  head_kernel<<<(B_*PRED_+3)/4, 256, 0, stream>>>(
      x, P + PO_FNW, P + PO_FNB, P + PO_HEADW, meanv, stdv, d_out, (const u16*)d_in[6]);
}

// Round 13
// 464.279 us; speedup vs baseline: 2.4180x; 2.4180x over previous
//
#include <hip/hip_runtime.h>

#define B_    16
#define LBL_  48
#define PRED_ 336
#define CIN_  7
#define L_    384
#define DM_   512
#define E_    2
#define DIN_  1024
#define N_    16
#define DCONV_ 4
#define DTR_  32
#define TF_   4
#define EPSF  1e-5f
#define NSEG  8
#define SEGL  48
#define SC4   4
#define NCHK  12

typedef unsigned short u16;
typedef __attribute__((ext_vector_type(8))) short short8;
typedef __attribute__((ext_vector_type(4))) float f32x4;

__device__ __forceinline__ float bf2f(u16 u){
  union { float f; unsigned int i; } cv; cv.i = ((unsigned int)u) << 16; return cv.f;
}
__device__ __forceinline__ u16 f2bf(float f){
  union { float f; unsigned int i; } cv; cv.f = f;
  unsigned int x = cv.i;
  unsigned int lsb = (x >> 16) & 1u;
  x += 0x7fffu + lsb;
  return (u16)(x >> 16);
}
__device__ __forceinline__ float lo16(unsigned int v){
  union { float f; unsigned int i; } cv; cv.i = v << 16; return cv.f;
}
__device__ __forceinline__ float hi16(unsigned int v){
  union { float f; unsigned int i; } cv; cv.i = v & 0xffff0000u; return cv.f;
}

#define GLDS(g, l) __builtin_amdgcn_global_load_lds( \
    (const __attribute__((address_space(1))) void*)(g), \
    (__attribute__((address_space(3))) void*)(l), 16, 0, 0)

// ---- fp32 parameter block offsets inside d_ws (floats) ----
#define PO_XDEC   0
#define PO_XMARK  43008
#define PO_TOKW   67584
#define PO_TIMEF  78336
#define PO_NORMW  80384
#define PO_NORMB  81408
#define PO_INW    82432
#define PO_CONVW  2179584
#define PO_CONVB  2187776
#define PO_XPROJ  2189824
#define PO_DTW    2320896
#define PO_DTB    2386432
#define PO_ALOG   2388480
#define PO_DP     2421248
#define PO_OUTW   2423296
#define PO_FNW    3471872
#define PO_FNB    3472384
#define PO_HEADW  3472896
#define P_TOTAL   3476480
// ---- activation offsets (floats) ----
#define A_X    3476480
#define A_LNB  6622208
#define A_XZ   9767936
#define A_DT   22350848
#define A_DBC  28642304
#define A_XD   29035520
#define A_MEAN 29078528
#define A_STD  29078640

struct Ptrs { const void* p[18]; };

__device__ __forceinline__ float wredsum(float s){
  #pragma unroll
  for (int off = 32; off; off >>= 1) s += __shfl_xor(s, off, 64);
  return s;
}

__device__ __forceinline__ void qpowers(float q, float* p){
  float q2 = q*q;
  float q4 = q2*q2;
  float q8 = q4*q4;
  float q3 = q2*q;
  p[0]=q;      p[1]=q2;     p[2]=q3;     p[3]=q4;
  p[4]=q4*q;   p[5]=q4*q2;  p[6]=q4*q3;  p[7]=q8;
  p[8]=q8*q;   p[9]=q8*q2;  p[10]=q8*q3; p[11]=q8*q4;
  p[12]=q8*p[4]; p[13]=q8*p[5]; p[14]=q8*p[6]; p[15]=q8*q8;
}

// ---------------- dtype-agnostic input conversion ----------------
__global__ __launch_bounds__(256) void convert_kernel(Ptrs ps, float* __restrict__ dst){
  const int offs[18] = {PO_XDEC, PO_XMARK, PO_TOKW, PO_TIMEF, PO_NORMW, PO_NORMB,
                        PO_INW, PO_CONVW, PO_CONVB, PO_XPROJ, PO_DTW, PO_DTB,
                        PO_ALOG, PO_DP, PO_OUTW, PO_FNW, PO_FNB, PO_HEADW};
  int idx = blockIdx.x * 256 + threadIdx.x;
  if (idx >= P_TOTAL) return;
  int seg = 0;
  #pragma unroll
  for (int s = 1; s < 18; s++) if (idx >= offs[s]) seg = s;
  int off = idx - offs[seg];
  int isbf = (((const u16*)ps.p[4])[0] == 0x3F80u);
  if (seg == 6 || seg == 9 || seg == 14){
    u16 hv = isbf ? ((const u16*)ps.p[seg])[off]
                  : f2bf(((const float*)ps.p[seg])[off]);
    ((u16*)(dst + offs[seg]))[off] = hv;
  } else {
    float v = isbf ? bf2f(((const u16*)ps.p[seg])[off])
                   : ((const float*)ps.p[seg])[off];
    dst[idx] = v;
  }
}

// ---------------- prep: head normalization + mean/std (one wave per (b,c)) ----------------
__global__ __launch_bounds__(64) void prep_kernel(const float* __restrict__ x_dec, float* __restrict__ xd,
                            float* __restrict__ meanv, float* __restrict__ stdv){
  int i = blockIdx.x;
  int b = i / CIN_, c = i % CIN_;
  int lane = threadIdx.x;
  float v0 = (lane < LBL_) ? x_dec[(b*L_+lane)*CIN_+c] : 0.f;
  float m = wredsum(v0) * (1.f/LBL_);
  float dv = (lane < LBL_) ? (v0 - m) : 0.f;
  float sd = sqrtf(wredsum(dv*dv) * (1.f/LBL_) + EPSF);
  if (lane == 0){ meanv[i] = m; stdv[i] = sd; }
  float inv = 1.f / sd;
  #pragma unroll
  for (int t = lane; t < L_; t += 64){
    float v = x_dec[(b*L_+t)*CIN_+c];
    xd[(b*L_+t)*CIN_+c] = (t < LBL_) ? (v - m) * inv : v;
  }
}

// ---------------- fused token embed + LayerNorm(e=0): wave per token ----------------
// Writes fp32 x (residual stream) and bf16 lnxb (in_proj input) in one pass.
__global__ __launch_bounds__(256) void embed_ln_kernel(const float* __restrict__ xd,
      const float* __restrict__ token_w, const float* __restrict__ x_mark,
      const float* __restrict__ timef_w, const float* __restrict__ nw,
      const float* __restrict__ nb, float* __restrict__ x, u16* __restrict__ out){
  int tok = blockIdx.x*4 + (threadIdx.x >> 6);
  int lane = threadIdx.x & 63;
  int t = tok % L_;
  int b = tok / L_;
  int tm1 = (t == 0) ? L_-1 : t-1;
  int tp1 = (t == L_-1) ? 0 : t+1;
  const float* r0 = xd + (b*L_+tm1)*CIN_;
  const float* r1 = xd + (b*L_+t  )*CIN_;
  const float* r2 = xd + (b*L_+tp1)*CIN_;
  const float* mk = x_mark + (b*L_+t)*TF_;
  float a0[CIN_], a1[CIN_], a2[CIN_], mkv[TF_];
  #pragma unroll
  for (int ci = 0; ci < CIN_; ci++){ a0[ci]=r0[ci]; a1[ci]=r1[ci]; a2[ci]=r2[ci]; }
  #pragma unroll
  for (int f = 0; f < TF_; f++) mkv[f] = mk[f];
  float v[8];
  #pragma unroll
  for (int j = 0; j < 8; j++){
    int d = lane*8 + j;
    float acc = 0.f;
    #pragma unroll
    for (int ci = 0; ci < CIN_; ci++){
      const float* w = token_w + (d*CIN_+ci)*3;
      acc += a0[ci]*w[0] + a1[ci]*w[1] + a2[ci]*w[2];
    }
    #pragma unroll
    for (int f = 0; f < TF_; f++)
      acc += mkv[f] * timef_w[d*TF_+f];
    v[j] = acc;
  }
  // write x (fp32 residual)
  float* xr = x + (size_t)tok*DM_ + lane*8;
  *(float4*)xr       = (float4){v[0],v[1],v[2],v[3]};
  *(float4*)(xr + 4) = (float4){v[4],v[5],v[6],v[7]};
  // LN
  float s = (v[0]+v[1])+(v[2]+v[3])+((v[4]+v[5])+(v[6]+v[7]));
  float mean = wredsum(s) * (1.f/DM_);
  float s2 = 0.f;
  #pragma unroll
  for (int j = 0; j < 8; j++){ v[j] -= mean; s2 += v[j]*v[j]; }
  float rstd = rsqrtf(wredsum(s2) * (1.f/DM_) + EPSF);
  const float* wr = nw + lane*8;
  const float* br = nb + lane*8;
  uint4 o; unsigned int* op = (unsigned int*)&o;
  #pragma unroll
  for (int k = 0; k < 4; k++){
    u16 e0 = f2bf(v[2*k]   * rstd * wr[2*k]   + br[2*k]);
    u16 e1 = f2bf(v[2*k+1] * rstd * wr[2*k+1] + br[2*k+1]);
    op[k] = (unsigned int)e0 | ((unsigned int)e1 << 16);
  }
  *(uint4*)(out + (size_t)tok*DM_ + lane*8) = o;
}

// ---------------- layer norm over DM=512 -> bf16, wave per token ----------------
__global__ __launch_bounds__(256) void ln_kernel(const float* __restrict__ x,
     const float* __restrict__ w, const float* __restrict__ bias, u16* __restrict__ out){
  int tok = blockIdx.x*4 + (threadIdx.x >> 6);
  int lane = threadIdx.x & 63;
  const float* xr = x + (size_t)tok*DM_ + lane*8;
  float4 a = *(const float4*)xr;
  float4 bq = *(const float4*)(xr + 4);
  float v[8] = {a.x,a.y,a.z,a.w,bq.x,bq.y,bq.z,bq.w};
  float s = (v[0]+v[1])+(v[2]+v[3])+((v[4]+v[5])+(v[6]+v[7]));
  float mean = wredsum(s) * (1.f/DM_);
  float s2 = 0.f;
  #pragma unroll
  for (int j = 0; j < 8; j++){ v[j] -= mean; s2 += v[j]*v[j]; }
  float rstd = rsqrtf(wredsum(s2) * (1.f/DM_) + EPSF);
  const float* wr = w + lane*8;
  const float* br = bias + lane*8;
  uint4 o; unsigned int* op = (unsigned int*)&o;
  #pragma unroll
  for (int k = 0; k < 4; k++){
    u16 e0 = f2bf(v[2*k]   * rstd * wr[2*k]   + br[2*k]);
    u16 e1 = f2bf(v[2*k+1] * rstd * wr[2*k+1] + br[2*k+1]);
    op[k] = (unsigned int)e0 | ((unsigned int)e1 << 16);
  }
  *(uint4*)(out + (size_t)tok*DM_ + lane*8) = o;
}

// ---------------- MFMA GEMM: C[M,N] (+)= A[M,K](bf16) * W[N,K](bf16)^T ----------------
// global_load_lds width-16 staging into UNPADDED [rows][32] u16 tiles.
template<int TN, int ACCUM, int BF16OUT>
__global__ __launch_bounds__(256) void gemm_mfma(const u16* __restrict__ A, const u16* __restrict__ Wt,
    void* __restrict__ C, int M, int N, int K){
  constexpr int WN = TN / 2;
  constexpr int NI = WN / 16;
  __shared__ u16 As[128 * 32];
  __shared__ u16 Ws[TN * 32];
  int tid = threadIdx.x;
  int wv = tid >> 6, lane = tid & 63;
  int wm = (wv & 1) * 64, wn = (wv >> 1) * WN;
  int m0 = blockIdx.y * 128, n0 = blockIdx.x * TN;
  int la = lane & 15, lk = lane >> 4;
  f32x4 acc[4][NI];
  #pragma unroll
  for (int i = 0; i < 4; i++)
    #pragma unroll
    for (int j = 0; j < NI; j++) acc[i][j] = (f32x4){0.f, 0.f, 0.f, 0.f};
  int srow = lane >> 2, scol = (lane & 3) * 8;
  const u16* Ag0 = A + (size_t)(m0 + wv*32 + srow) * K + scol;
  const u16* Ag1 = Ag0 + (size_t)16 * K;
  u16* Al0 = As + wv*1024 + lane*8;
  u16* Al1 = As + wv*1024 + 512 + lane*8;
  const u16 *Wg0, *Wg1;
  u16 *Wl0, *Wl1;
  if constexpr (TN == 128){
    Wg0 = Wt + (size_t)(n0 + wv*32 + srow) * K + scol;
    Wg1 = Wg0 + (size_t)16 * K;
    Wl0 = Ws + wv*1024 + lane*8;
    Wl1 = Ws + wv*1024 + 512 + lane*8;
  } else {
    Wg0 = Wt + (size_t)(n0 + wv*16 + srow) * K + scol;
    Wg1 = nullptr;
    Wl0 = Ws + wv*512 + lane*8;
    Wl1 = nullptr;
  }
  for (int k0 = 0; k0 < K; k0 += 32){
    GLDS(Ag0 + k0, Al0);
    GLDS(Ag1 + k0, Al1);
    GLDS(Wg0 + k0, Wl0);
    if constexpr (TN == 128) GLDS(Wg1 + k0, Wl1);
    __syncthreads();
    short8 af[4], bfr[NI];
    #pragma unroll
    for (int mi = 0; mi < 4; mi++) af[mi] = *(const short8*)&As[(wm + mi*16 + la)*32 + lk*8];
    #pragma unroll
    for (int ni = 0; ni < NI; ni++) bfr[ni] = *(const short8*)&Ws[(wn + ni*16 + la)*32 + lk*8];
    #pragma unroll
    for (int mi = 0; mi < 4; mi++)
      #pragma unroll
      for (int ni = 0; ni < NI; ni++)
        acc[mi][ni] = __builtin_amdgcn_mfma_f32_16x16x32_bf16(af[mi], bfr[ni], acc[mi][ni], 0, 0, 0);
    __syncthreads();
  }
  #pragma unroll
  for (int mi = 0; mi < 4; mi++)
    #pragma unroll
    for (int ni = 0; ni < NI; ni++){
      int row = m0 + wm + mi*16 + lk*4;
      int col = n0 + wn + ni*16 + la;
      #pragma unroll
      for (int r = 0; r < 4; r++){
        if constexpr (BF16OUT){
          u16* p = (u16*)C + (size_t)row * N + col;
          p[(size_t)r * N] = f2bf(acc[mi][ni][r]);
        } else {
          float* p = (float*)C + (size_t)row * N + col;
          if (ACCUM) p[(size_t)r * N] += acc[mi][ni][r];
          else       p[(size_t)r * N]  = acc[mi][ni][r];
        }
      }
    }
}

// ---------------- depthwise causal conv (k=4) + SiLU: 8 channels/thread ----------------
__global__ __launch_bounds__(256) void conv_silu_kernel(const u16* __restrict__ xz,
   const float* __restrict__ cw, const float* __restrict__ cb, u16* __restrict__ xcb){
  int e = blockIdx.x * 256 + threadIdx.x;
  int c8 = (e & (DIN_/8 - 1)) * 8;
  int bt = e >> 7;
  int t  = bt % L_;
  const u16* base = xz + (size_t)bt * (2*DIN_) + c8;
  uint4 tap[4];
  tap[3] = *(const uint4*)base;
  if (t >= 1) tap[2] = *(const uint4*)(base - 1*2*DIN_);
  if (t >= 2) tap[1] = *(const uint4*)(base - 2*2*DIN_);
  if (t >= 3) tap[0] = *(const uint4*)(base - 3*2*DIN_);
  float v[8];
  #pragma unroll
  for (int k = 0; k < 8; k++){
    float4 w = *(const float4*)(cw + (c8 + k)*4);
    float s = cb[c8 + k];
    #pragma unroll
    for (int j = 0; j < 4; j++){
      if (j >= 3 - t){
        const unsigned int* tp = (const unsigned int*)&tap[j];
        float xv = (k & 1) ? hi16(tp[k >> 1]) : lo16(tp[k >> 1]);
        s += xv * ((const float*)&w)[j];
      }
    }
    v[k] = s / (1.f + __expf(-s));
  }
  uint4 o;
  unsigned int* op = (unsigned int*)&o;
  #pragma unroll
  for (int k = 0; k < 4; k++)
    op[k] = (unsigned int)f2bf(v[2*k]) | ((unsigned int)f2bf(v[2*k+1]) << 16);
  *(uint4*)(xcb + (size_t)bt * DIN_ + c8) = o;
}

// ---------------- dt projection + softplus -> dt bf16 [tok][1024] ----------------
__global__ __launch_bounds__(256) void dtproj_kernel(const float* __restrict__ dbc,
    const float* __restrict__ dtw, const float* __restrict__ dtb, u16* __restrict__ dt){
  __shared__ float r[32][33];
  int tid = threadIdx.x;
  int tok0 = blockIdx.y * 32;
  int d = blockIdx.x * 256 + tid;
  {
    int t = tid >> 3, col = (tid & 7) * 4;
    *(float4*)&r[t][col] = *(const float4*)(dbc + (size_t)(tok0 + t)*64 + col);
  }
  __syncthreads();
  float w[32];
  #pragma unroll
  for (int k = 0; k < 32; k += 4){
    float4 wv = *(const float4*)(dtw + (size_t)d*DTR_ + k);
    w[k] = wv.x; w[k+1] = wv.y; w[k+2] = wv.z; w[k+3] = wv.w;
  }
  float bias = dtb[d];
  for (int t = 0; t < 32; t++){
    float acc = bias;
    #pragma unroll
    for (int k = 0; k < 32; k++) acc += w[k] * r[t][k];
    float sp = (acc > 20.f) ? acc : log1pf(__expf(acc));
    dt[(size_t)(tok0 + t) * DIN_ + d] = f2bf(sp);
  }
}

// ---------------- selective scan: 8 segments x 48 steps, 2-pass, 16 states/thread ----------------
#define WST4 1792
__global__ __launch_bounds__(512, 1) void scan_kernel(
    u16* __restrict__ ub_yb,
    const float* __restrict__ dbc, const u16* __restrict__ xz,
    const u16* __restrict__ dtp,
    const float* __restrict__ A_log, const float* __restrict__ Dp){
  __shared__ float smem[16384];

  int tid = threadIdx.x;
  int lane = tid & 63;
  int seg  = tid >> 6;
  int b = blockIdx.x >> 4;
  int g = blockIdx.x & 15;
  int d = g*64 + lane;
  size_t base = (size_t)b * L_;

  float* wbase = smem + seg * WST4;
  float* sbc = wbase;
  float* su  = wbase + 256;
  float* sz  = wbase + 768;
  float* sdt = wbase + 1280;

  int st  = lane >> 4;
  int c16 = lane & 15;

  float A[16];
  #pragma unroll
  for (int n = 0; n < 16; n += 4){
    float4 av = *(const float4*)(A_log + (size_t)d*N_ + n);
    A[n] = -__expf(av.x); A[n+1] = -__expf(av.y); A[n+2] = -__expf(av.z); A[n+3] = -__expf(av.w);
  }
  float Dv = Dp[d];
  bool fastA = true;
  #pragma unroll
  for (int n = 0; n < 16; n++) fastA = fastA && (fabsf(A[n] + (float)(n+1)) < 1e-3f*(n+1));

  float h[16];
  #pragma unroll
  for (int n = 0; n < 16; n++) h[n] = 0.f;

  auto ldc = [&](int c, float2& kbc, uint2& ku, uint2& kz, uint2& kt, bool wz){
    size_t tokr = base + seg*SEGL + c*SC4 + st;
    kbc = *(const float2*)(dbc + tokr*64 + 32 + c16*2);
    ku  = *(const uint2*)(ub_yb + tokr*DIN_ + g*64 + c16*4);
    kt  = *(const uint2*)(dtp + tokr*DIN_ + g*64 + c16*4);
    if (wz) kz = *(const uint2*)(xz + tokr*(2*DIN_) + DIN_ + g*64 + c16*4);
  };
  auto cvt4 = [&](const uint2& v, float* dst){
    dst[0] = lo16(v.x); dst[1] = hi16(v.x);
    dst[2] = lo16(v.y); dst[3] = hi16(v.y);
  };
  auto stc = [&](int buf, const float2& kbc, const uint2& ku, const uint2& kz,
                 const uint2& kt, bool wz){
    *(float2*)&sbc[buf*128 + st*32 + c16*2] = kbc;
    cvt4(ku, &su[buf*256 + st*64 + c16*4]);
    cvt4(kt, &sdt[buf*256 + st*64 + c16*4]);
    if (wz) cvt4(kz, &sz[buf*256 + st*64 + c16*4]);
  };

  // PASS 1
  float S = 0.f;
  {
    float2 kbc; uint2 ku, kz, kt;
    ldc(0, kbc, ku, kz, kt, false);
    stc(0, kbc, ku, kz, kt, false);
    for (int c = 0; c < NCHK; c++){
      int cur = c & 1;
      bool have = (c + 1 < NCHK);
      float2 nbc; uint2 nu, nz, nt;
      if (have) ldc(c+1, nbc, nu, nz, nt, false);
      for (int s = 0; s < SC4; s++){
        float dtv = sdt[cur*256 + s*64 + lane];
        float u   = su [cur*256 + s*64 + lane];
        const float* bcrow = sbc + cur*128 + s*32;
        float Bf[16];
        #pragma unroll
        for (int i = 0; i < 16; i += 4){
          float4 bv = *(const float4*)(bcrow + i);
          Bf[i] = bv.x; Bf[i+1] = bv.y; Bf[i+2] = bv.z; Bf[i+3] = bv.w;
        }
        float du = dtv * u;
        S += dtv;
        if (fastA){
          float q = __expf(-dtv);
          float p[16];
          qpowers(q, p);
          #pragma unroll
          for (int n = 0; n < 16; n++) h[n] = p[n] * h[n] + du * Bf[n];
        } else {
          #pragma unroll
          for (int n = 0; n < 16; n++){
            float dA = __expf(dtv * A[n]);
            h[n] = dA * h[n] + du * Bf[n];
          }
        }
      }
      if (have) stc(1 - cur, nbc, nu, nz, nt, false);
    }
  }

  // combine
  __syncthreads();
  #pragma unroll
  for (int n = 0; n < 16; n++){
    smem[(n*NSEG + seg)*64 + lane]        = h[n];
    smem[8192 + (n*NSEG + seg)*64 + lane] = __expf(A[n] * S);
  }
  __syncthreads();
  {
    float hs[16];
    #pragma unroll
    for (int n = 0; n < 16; n++) hs[n] = 0.f;
    for (int j = 0; j < seg; j++){
      #pragma unroll
      for (int n = 0; n < 16; n++){
        float qh = smem[(n*NSEG + j)*64 + lane];
        float qP = smem[8192 + (n*NSEG + j)*64 + lane];
        hs[n] = qh + qP * hs[n];
      }
    }
    #pragma unroll
    for (int n = 0; n < 16; n++) h[n] = hs[n];
  }
  __syncthreads();

  // PASS 2
  {
    float2 kbc; uint2 ku, kz, kt;
    ldc(0, kbc, ku, kz, kt, true);
    stc(0, kbc, ku, kz, kt, true);
    for (int c = 0; c < NCHK; c++){
      int cur = c & 1;
      bool have = (c + 1 < NCHK);
      float2 nbc; uint2 nu, nz, nt;
      if (have) ldc(c+1, nbc, nu, nz, nt, true);
      for (int s = 0; s < SC4; s++){
        float dtv = sdt[cur*256 + s*64 + lane];
        float u   = su [cur*256 + s*64 + lane];
        float z   = sz [cur*256 + s*64 + lane];
        const float* bcrow = sbc + cur*128 + s*32;
        float Bf[16], Cf[16];
        #pragma unroll
        for (int i = 0; i < 16; i += 4){
          float4 bv = *(const float4*)(bcrow + i);
          float4 cv = *(const float4*)(bcrow + 16 + i);
          Bf[i] = bv.x; Bf[i+1] = bv.y; Bf[i+2] = bv.z; Bf[i+3] = bv.w;
          Cf[i] = cv.x; Cf[i+1] = cv.y; Cf[i+2] = cv.z; Cf[i+3] = cv.w;
        }
        float du = dtv * u;
        float acc = 0.f;
        if (fastA){
          float q = __expf(-dtv);
          float p[16];
          qpowers(q, p);
          #pragma unroll
          for (int n = 0; n < 16; n++){
            h[n] = p[n] * h[n] + du * Bf[n];
            acc += h[n] * Cf[n];
          }
        } else {
          #pragma unroll
          for (int n = 0; n < 16; n++){
            float dA = __expf(dtv * A[n]);
            h[n] = dA * h[n] + du * Bf[n];
            acc += h[n] * Cf[n];
          }
        }
        float y = acc + u * Dv;
        size_t tok = base + seg*SEGL + c*SC4 + s;
        ub_yb[tok*DIN_ + d] = f2bf(y * (z / (1.f + __expf(-z))));
      }
      if (have) stc(1 - cur, nbc, nu, nz, nt, true);
    }
  }
}

// ---------------- final LN + 512->7 head + de-normalize, wave per token ----------------
__global__ __launch_bounds__(256) void head_kernel(const float* __restrict__ x,
    const float* __restrict__ fw, const float* __restrict__ fb, const float* __restrict__ ow,
    const float* __restrict__ meanv, const float* __restrict__ stdv, void* __restrict__ out,
    const u16* __restrict__ dtype_probe){
  int wav = blockIdx.x*4 + (threadIdx.x >> 6);
  int lane = threadIdx.x & 63;
  if (wav >= B_*PRED_) return;
  int b = wav / PRED_;
  int tt = wav % PRED_;
  int tok = b*L_ + LBL_ + tt;
  const float* xr = x + (size_t)tok*DM_ + lane*8;
  float4 a = *(const float4*)xr;
  float4 bq = *(const float4*)(xr + 4);
  float v[8] = {a.x,a.y,a.z,a.w,bq.x,bq.y,bq.z,bq.w};
  float s = (v[0]+v[1])+(v[2]+v[3])+((v[4]+v[5])+(v[6]+v[7]));
  float mean = wredsum(s) * (1.f/DM_);
  float s2 = 0.f;
  #pragma unroll
  for (int j = 0; j < 8; j++){ v[j] -= mean; s2 += v[j]*v[j]; }
  float rstd = rsqrtf(wredsum(s2) * (1.f/DM_) + EPSF);
  const float* fwr = fw + lane*8;
  const float* fbr = fb + lane*8;
  #pragma unroll
  for (int j = 0; j < 8; j++) v[j] = v[j] * rstd * fwr[j] + fbr[j];
  int isbf = (dtype_probe[0] == 0x3F80u);
  for (int o = 0; o < CIN_; o++){
    const float* owr = ow + (size_t)o*DM_ + lane*8;
    float part = 0.f;
    #pragma unroll
    for (int j = 0; j < 8; j++) part += v[j] * owr[j];
    part = wredsum(part);
    if (lane == 0){
      float res = part * stdv[b*CIN_ + o] + meanv[b*CIN_ + o];
      size_t oidx = (size_t)(b*PRED_ + tt)*CIN_ + o;
      if (isbf) ((u16*)out)[oidx] = f2bf(res);
      else      ((float*)out)[oidx] = res;
    }
  }
}

extern "C" void kernel_launch(void* const* d_in, const int* in_sizes, int n_in,
                              void* d_out, int out_size, void* d_ws, size_t ws_size,
                              hipStream_t stream){
  float* P = (float*)d_ws;

  Ptrs ps;
  for (int i = 0; i < 18; i++) ps.p[i] = d_in[2 + i];

  float* x    = P + A_X;
  u16*   lnxb = (u16*)(P + A_LNB);
  u16*   xcb  = (u16*)(P + A_LNB);
  u16*   xz   = (u16*)(P + A_XZ);
  u16*   dt   = (u16*)(P + A_DT);
  float* dbc  = P + A_DBC;
  float* xd   = P + A_XD;
  float* meanv= P + A_MEAN;
  float* stdv = P + A_STD;
  const u16* bwi = (const u16*)(P + PO_INW);
  const u16* bwx = (const u16*)(P + PO_XPROJ);
  const u16* bwo = (const u16*)(P + PO_OUTW);

  convert_kernel<<<(P_TOTAL+255)/256, 256, 0, stream>>>(ps, P);
  prep_kernel<<<B_*CIN_, 64, 0, stream>>>(P + PO_XDEC, xd, meanv, stdv);
  embed_ln_kernel<<<(B_*L_)/4, 256, 0, stream>>>(
      xd, P + PO_TOKW, P + PO_XMARK, P + PO_TIMEF,
      P + PO_NORMW, P + PO_NORMB, x, lnxb);

  for (int e = 0; e < E_; e++){
    if (e > 0)
      ln_kernel<<<(B_*L_)/4, 256, 0, stream>>>(x, P + PO_NORMW + e*DM_, P + PO_NORMB + e*DM_, lnxb);
    gemm_mfma<128,0,1><<<dim3((2*DIN_)/128, (B_*L_)/128), 256, 0, stream>>>(
        lnxb, bwi + (size_t)e*2*DIN_*DM_, xz, B_*L_, 2*DIN_, DM_);
    conv_silu_kernel<<<(B_*L_*DIN_)/(256*8), 256, 0, stream>>>(
        xz, P + PO_CONVW + e*DIN_*DCONV_, P + PO_CONVB + e*DIN_, xcb);
    gemm_mfma<64,0,0><<<dim3(1, (B_*L_)/128), 256, 0, stream>>>(
        xcb, bwx + (size_t)e*64*DIN_, dbc, B_*L_, 64, DIN_);
    dtproj_kernel<<<dim3(DIN_/256, (B_*L_)/32), 256, 0, stream>>>(
        dbc, P + PO_DTW + e*DIN_*DTR_, P + PO_DTB + e*DIN_, dt);
    scan_kernel<<<256, 512, 0, stream>>>(
        xcb, dbc, xz, dt, P + PO_ALOG + e*DIN_*N_, P + PO_DP + e*DIN_);
    gemm_mfma<64,1,0><<<dim3(DM_/64, (B_*L_)/128), 256, 0, stream>>>(
        xcb, bwo + (size_t)e*DM_*DIN_, x, B_*L_, DM_, DIN_);
  }

  head_kernel<<<(B_*PRED_+3)/4, 256, 0, stream>>>(
      x, P + PO_FNW, P + PO_FNB, P + PO_HEADW, meanv, stdv, d_out, (const u16*)d_in[6]);
}

// Round 14
// 451.030 us; speedup vs baseline: 2.4890x; 1.0294x over previous
//
#include <hip/hip_runtime.h>

#define B_    16
#define LBL_  48
#define PRED_ 336
#define CIN_  7
#define L_    384
#define DM_   512
#define E_    2
#define DIN_  1024
#define N_    16
#define DCONV_ 4
#define DTR_  32
#define TF_   4
#define EPSF  1e-5f
// scan: 16 segments x 24 steps, chunks of 2
#define NSEG  16
#define SEGL  24
#define SC2   2
#define NCHK  12

typedef unsigned short u16;
typedef __attribute__((ext_vector_type(8))) short short8;
typedef __attribute__((ext_vector_type(4))) float f32x4;

__device__ __forceinline__ float bf2f(u16 u){
  union { float f; unsigned int i; } cv; cv.i = ((unsigned int)u) << 16; return cv.f;
}
__device__ __forceinline__ u16 f2bf(float f){
  union { float f; unsigned int i; } cv; cv.f = f;
  unsigned int x = cv.i;
  unsigned int lsb = (x >> 16) & 1u;
  x += 0x7fffu + lsb;
  return (u16)(x >> 16);
}
__device__ __forceinline__ float lo16(unsigned int v){
  union { float f; unsigned int i; } cv; cv.i = v << 16; return cv.f;
}
__device__ __forceinline__ float hi16(unsigned int v){
  union { float f; unsigned int i; } cv; cv.i = v & 0xffff0000u; return cv.f;
}

#define GLDS(g, l) __builtin_amdgcn_global_load_lds( \
    (const __attribute__((address_space(1))) void*)(g), \
    (__attribute__((address_space(3))) void*)(l), 16, 0, 0)

// ---- fp32 parameter block offsets inside d_ws (floats) ----
// INW/XPROJ/DTW/OUTW slots hold bf16 (u16) weights.
#define PO_XDEC   0
#define PO_XMARK  43008
#define PO_TOKW   67584
#define PO_TIMEF  78336
#define PO_NORMW  80384
#define PO_NORMB  81408
#define PO_INW    82432
#define PO_CONVW  2179584
#define PO_CONVB  2187776
#define PO_XPROJ  2189824
#define PO_DTW    2320896
#define PO_DTB    2386432
#define PO_ALOG   2388480
#define PO_DP     2421248
#define PO_OUTW   2423296
#define PO_FNW    3471872
#define PO_FNB    3472384
#define PO_HEADW  3472896
#define P_TOTAL   3476480
// ---- activation offsets (floats) ----
#define A_X    3476480
#define A_LNB  6622208
#define A_XZ   9767936
#define A_DT   22350848
#define A_DBC  28642304
#define A_XD   29035520
#define A_MEAN 29078528
#define A_STD  29078640
#define A_DTR  29100032   /* bf16 [6144][32] dt_r side-buffer */

struct Ptrs { const void* p[18]; };

__device__ __forceinline__ float wredsum(float s){
  #pragma unroll
  for (int off = 32; off; off >>= 1) s += __shfl_xor(s, off, 64);
  return s;
}

__device__ __forceinline__ void qpowers(float q, float* p){
  float q2 = q*q;
  float q4 = q2*q2;
  float q8 = q4*q4;
  float q3 = q2*q;
  p[0]=q;      p[1]=q2;     p[2]=q3;     p[3]=q4;
  p[4]=q4*q;   p[5]=q4*q2;  p[6]=q4*q3;  p[7]=q8;
  p[8]=q8*q;   p[9]=q8*q2;  p[10]=q8*q3; p[11]=q8*q4;
  p[12]=q8*p[4]; p[13]=q8*p[5]; p[14]=q8*p[6]; p[15]=q8*q8;
}

// ---------------- dtype-agnostic input conversion ----------------
__global__ __launch_bounds__(256) void convert_kernel(Ptrs ps, float* __restrict__ dst){
  const int offs[18] = {PO_XDEC, PO_XMARK, PO_TOKW, PO_TIMEF, PO_NORMW, PO_NORMB,
                        PO_INW, PO_CONVW, PO_CONVB, PO_XPROJ, PO_DTW, PO_DTB,
                        PO_ALOG, PO_DP, PO_OUTW, PO_FNW, PO_FNB, PO_HEADW};
  int idx = blockIdx.x * 256 + threadIdx.x;
  if (idx >= P_TOTAL) return;
  int seg = 0;
  #pragma unroll
  for (int s = 1; s < 18; s++) if (idx >= offs[s]) seg = s;
  int off = idx - offs[seg];
  int isbf = (((const u16*)ps.p[4])[0] == 0x3F80u);
  if (seg == 6 || seg == 9 || seg == 10 || seg == 14){
    u16 hv = isbf ? ((const u16*)ps.p[seg])[off]
                  : f2bf(((const float*)ps.p[seg])[off]);
    ((u16*)(dst + offs[seg]))[off] = hv;
  } else {
    float v = isbf ? bf2f(((const u16*)ps.p[seg])[off])
                   : ((const float*)ps.p[seg])[off];
    dst[idx] = v;
  }
}

// ---------------- prep: head normalization + mean/std (one wave per (b,c)) ----------------
__global__ __launch_bounds__(64) void prep_kernel(const float* __restrict__ x_dec, float* __restrict__ xd,
                            float* __restrict__ meanv, float* __restrict__ stdv){
  int i = blockIdx.x;
  int b = i / CIN_, c = i % CIN_;
  int lane = threadIdx.x;
  float v0 = (lane < LBL_) ? x_dec[(b*L_+lane)*CIN_+c] : 0.f;
  float m = wredsum(v0) * (1.f/LBL_);
  float dv = (lane < LBL_) ? (v0 - m) : 0.f;
  float sd = sqrtf(wredsum(dv*dv) * (1.f/LBL_) + EPSF);
  if (lane == 0){ meanv[i] = m; stdv[i] = sd; }
  float inv = 1.f / sd;
  #pragma unroll
  for (int t = lane; t < L_; t += 64){
    float v = x_dec[(b*L_+t)*CIN_+c];
    xd[(b*L_+t)*CIN_+c] = (t < LBL_) ? (v - m) * inv : v;
  }
}

// ---------------- fused token embed + LayerNorm(e=0): wave per token ----------------
__global__ __launch_bounds__(256) void embed_ln_kernel(const float* __restrict__ xd,
      const float* __restrict__ token_w, const float* __restrict__ x_mark,
      const float* __restrict__ timef_w, const float* __restrict__ nw,
      const float* __restrict__ nb, float* __restrict__ x, u16* __restrict__ out){
  int tok = blockIdx.x*4 + (threadIdx.x >> 6);
  int lane = threadIdx.x & 63;
  int t = tok % L_;
  int b = tok / L_;
  int tm1 = (t == 0) ? L_-1 : t-1;
  int tp1 = (t == L_-1) ? 0 : t+1;
  const float* r0 = xd + (b*L_+tm1)*CIN_;
  const float* r1 = xd + (b*L_+t  )*CIN_;
  const float* r2 = xd + (b*L_+tp1)*CIN_;
  const float* mk = x_mark + (b*L_+t)*TF_;
  float a0[CIN_], a1[CIN_], a2[CIN_], mkv[TF_];
  #pragma unroll
  for (int ci = 0; ci < CIN_; ci++){ a0[ci]=r0[ci]; a1[ci]=r1[ci]; a2[ci]=r2[ci]; }
  #pragma unroll
  for (int f = 0; f < TF_; f++) mkv[f] = mk[f];
  float v[8];
  #pragma unroll
  for (int j = 0; j < 8; j++){
    int d = lane*8 + j;
    float acc = 0.f;
    #pragma unroll
    for (int ci = 0; ci < CIN_; ci++){
      const float* w = token_w + (d*CIN_+ci)*3;
      acc += a0[ci]*w[0] + a1[ci]*w[1] + a2[ci]*w[2];
    }
    #pragma unroll
    for (int f = 0; f < TF_; f++)
      acc += mkv[f] * timef_w[d*TF_+f];
    v[j] = acc;
  }
  float* xr = x + (size_t)tok*DM_ + lane*8;
  *(float4*)xr       = (float4){v[0],v[1],v[2],v[3]};
  *(float4*)(xr + 4) = (float4){v[4],v[5],v[6],v[7]};
  float s = (v[0]+v[1])+(v[2]+v[3])+((v[4]+v[5])+(v[6]+v[7]));
  float mean = wredsum(s) * (1.f/DM_);
  float s2 = 0.f;
  #pragma unroll
  for (int j = 0; j < 8; j++){ v[j] -= mean; s2 += v[j]*v[j]; }
  float rstd = rsqrtf(wredsum(s2) * (1.f/DM_) + EPSF);
  const float* wr = nw + lane*8;
  const float* br = nb + lane*8;
  uint4 o; unsigned int* op = (unsigned int*)&o;
  #pragma unroll
  for (int k = 0; k < 4; k++){
    u16 e0 = f2bf(v[2*k]   * rstd * wr[2*k]   + br[2*k]);
    u16 e1 = f2bf(v[2*k+1] * rstd * wr[2*k+1] + br[2*k+1]);
    op[k] = (unsigned int)e0 | ((unsigned int)e1 << 16);
  }
  *(uint4*)(out + (size_t)tok*DM_ + lane*8) = o;
}

// ---------------- layer norm over DM=512 -> bf16, wave per token ----------------
__global__ __launch_bounds__(256) void ln_kernel(const float* __restrict__ x,
     const float* __restrict__ w, const float* __restrict__ bias, u16* __restrict__ out){
  int tok = blockIdx.x*4 + (threadIdx.x >> 6);
  int lane = threadIdx.x & 63;
  const float* xr = x + (size_t)tok*DM_ + lane*8;
  float4 a = *(const float4*)xr;
  float4 bq = *(const float4*)(xr + 4);
  float v[8] = {a.x,a.y,a.z,a.w,bq.x,bq.y,bq.z,bq.w};
  float s = (v[0]+v[1])+(v[2]+v[3])+((v[4]+v[5])+(v[6]+v[7]));
  float mean = wredsum(s) * (1.f/DM_);
  float s2 = 0.f;
  #pragma unroll
  for (int j = 0; j < 8; j++){ v[j] -= mean; s2 += v[j]*v[j]; }
  float rstd = rsqrtf(wredsum(s2) * (1.f/DM_) + EPSF);
  const float* wr = w + lane*8;
  const float* br = bias + lane*8;
  uint4 o; unsigned int* op = (unsigned int*)&o;
  #pragma unroll
  for (int k = 0; k < 4; k++){
    u16 e0 = f2bf(v[2*k]   * rstd * wr[2*k]   + br[2*k]);
    u16 e1 = f2bf(v[2*k+1] * rstd * wr[2*k+1] + br[2*k+1]);
    op[k] = (unsigned int)e0 | ((unsigned int)e1 << 16);
  }
  *(uint4*)(out + (size_t)tok*DM_ + lane*8) = o;
}

// ---------------- MFMA GEMM: C[M,N] (+)= A[M,K](bf16) * W[N,K](bf16)^T ----------------
// DTR: additionally store cols 0..31 of acc as bf16 into dtrb [M][32] (xproj only).
template<int TN, int ACCUM, int BF16OUT, int DTR>
__global__ __launch_bounds__(256) void gemm_mfma(const u16* __restrict__ A, const u16* __restrict__ Wt,
    void* __restrict__ C, int M, int N, int K, u16* __restrict__ dtrb){
  constexpr int WN = TN / 2;
  constexpr int NI = WN / 16;
  __shared__ u16 As[128 * 32];
  __shared__ u16 Ws[TN * 32];
  int tid = threadIdx.x;
  int wv = tid >> 6, lane = tid & 63;
  int wm = (wv & 1) * 64, wn = (wv >> 1) * WN;
  int m0 = blockIdx.y * 128, n0 = blockIdx.x * TN;
  int la = lane & 15, lk = lane >> 4;
  f32x4 acc[4][NI];
  #pragma unroll
  for (int i = 0; i < 4; i++)
    #pragma unroll
    for (int j = 0; j < NI; j++) acc[i][j] = (f32x4){0.f, 0.f, 0.f, 0.f};
  int srow = lane >> 2, scol = (lane & 3) * 8;
  const u16* Ag0 = A + (size_t)(m0 + wv*32 + srow) * K + scol;
  const u16* Ag1 = Ag0 + (size_t)16 * K;
  u16* Al0 = As + wv*1024 + lane*8;
  u16* Al1 = As + wv*1024 + 512 + lane*8;
  const u16 *Wg0, *Wg1;
  u16 *Wl0, *Wl1;
  if constexpr (TN == 128){
    Wg0 = Wt + (size_t)(n0 + wv*32 + srow) * K + scol;
    Wg1 = Wg0 + (size_t)16 * K;
    Wl0 = Ws + wv*1024 + lane*8;
    Wl1 = Ws + wv*1024 + 512 + lane*8;
  } else {
    Wg0 = Wt + (size_t)(n0 + wv*16 + srow) * K + scol;
    Wg1 = nullptr;
    Wl0 = Ws + wv*512 + lane*8;
    Wl1 = nullptr;
  }
  for (int k0 = 0; k0 < K; k0 += 32){
    GLDS(Ag0 + k0, Al0);
    GLDS(Ag1 + k0, Al1);
    GLDS(Wg0 + k0, Wl0);
    if constexpr (TN == 128) GLDS(Wg1 + k0, Wl1);
    __syncthreads();
    short8 af[4], bfr[NI];
    #pragma unroll
    for (int mi = 0; mi < 4; mi++) af[mi] = *(const short8*)&As[(wm + mi*16 + la)*32 + lk*8];
    #pragma unroll
    for (int ni = 0; ni < NI; ni++) bfr[ni] = *(const short8*)&Ws[(wn + ni*16 + la)*32 + lk*8];
    #pragma unroll
    for (int mi = 0; mi < 4; mi++)
      #pragma unroll
      for (int ni = 0; ni < NI; ni++)
        acc[mi][ni] = __builtin_amdgcn_mfma_f32_16x16x32_bf16(af[mi], bfr[ni], acc[mi][ni], 0, 0, 0);
    __syncthreads();
  }
  #pragma unroll
  for (int mi = 0; mi < 4; mi++)
    #pragma unroll
    for (int ni = 0; ni < NI; ni++){
      int row = m0 + wm + mi*16 + lk*4;
      int col = n0 + wn + ni*16 + la;
      #pragma unroll
      for (int r = 0; r < 4; r++){
        if constexpr (BF16OUT){
          u16* p = (u16*)C + (size_t)row * N + col;
          p[(size_t)r * N] = f2bf(acc[mi][ni][r]);
        } else {
          float* p = (float*)C + (size_t)row * N + col;
          if (ACCUM) p[(size_t)r * N] += acc[mi][ni][r];
          else       p[(size_t)r * N]  = acc[mi][ni][r];
        }
      }
    }
  if constexpr (DTR){
    if (wn == 0){
      #pragma unroll
      for (int mi = 0; mi < 4; mi++)
        #pragma unroll
        for (int ni = 0; ni < NI; ni++){
          int row = m0 + wm + mi*16 + lk*4;
          int col = ni*16 + la;        // 0..31 = dt_r cols
          #pragma unroll
          for (int r = 0; r < 4; r++)
            dtrb[(size_t)(row + r)*32 + col] = f2bf(acc[mi][ni][r]);
        }
    }
  }
}

// ---------------- dtproj as MFMA: dt = softplus(dt_r @ dtw^T + b), K=32 ----------------
// grid (16, 48): block = 128 tokens x 64 channels, one MFMA per fragment.
__global__ __launch_bounds__(256) void dtproj_mfma(const u16* __restrict__ dtrb,
    const u16* __restrict__ dtwb, const float* __restrict__ dtb, u16* __restrict__ dt){
  __shared__ u16 As[128 * 32];
  __shared__ u16 Ws[64 * 32];
  int tid = threadIdx.x;
  int wv = tid >> 6, lane = tid & 63;
  int wm = (wv & 1) * 64, wn = (wv >> 1) * 32;
  int m0 = blockIdx.y * 128, n0 = blockIdx.x * 64;
  int la = lane & 15, lk = lane >> 4;
  int srow = lane >> 2, scol = (lane & 3) * 8;
  GLDS(dtrb + (size_t)(m0 + wv*32 + srow)*32 + scol,      As + wv*1024 + lane*8);
  GLDS(dtrb + (size_t)(m0 + wv*32 + 16 + srow)*32 + scol, As + wv*1024 + 512 + lane*8);
  GLDS(dtwb + (size_t)(n0 + wv*16 + srow)*32 + scol,      Ws + wv*512 + lane*8);
  __syncthreads();
  short8 af[4], bfr[2];
  #pragma unroll
  for (int mi = 0; mi < 4; mi++) af[mi] = *(const short8*)&As[(wm + mi*16 + la)*32 + lk*8];
  #pragma unroll
  for (int ni = 0; ni < 2; ni++) bfr[ni] = *(const short8*)&Ws[(wn + ni*16 + la)*32 + lk*8];
  #pragma unroll
  for (int mi = 0; mi < 4; mi++)
    #pragma unroll
    for (int ni = 0; ni < 2; ni++){
      f32x4 acc = (f32x4){0.f,0.f,0.f,0.f};
      acc = __builtin_amdgcn_mfma_f32_16x16x32_bf16(af[mi], bfr[ni], acc, 0, 0, 0);
      int row = m0 + wm + mi*16 + lk*4;
      int d   = n0 + wn + ni*16 + la;
      float bias = dtb[d];
      #pragma unroll
      for (int r = 0; r < 4; r++){
        float raw = acc[r] + bias;
        float sp = (raw > 20.f) ? raw : log1pf(__expf(raw));
        dt[(size_t)(row + r)*DIN_ + d] = f2bf(sp);
      }
    }
}

// ---------------- depthwise causal conv (k=4) + SiLU: 8 channels/thread ----------------
__global__ __launch_bounds__(256) void conv_silu_kernel(const u16* __restrict__ xz,
   const float* __restrict__ cw, const float* __restrict__ cb, u16* __restrict__ xcb){
  int e = blockIdx.x * 256 + threadIdx.x;
  int c8 = (e & (DIN_/8 - 1)) * 8;
  int bt = e >> 7;
  int t  = bt % L_;
  const u16* base = xz + (size_t)bt * (2*DIN_) + c8;
  uint4 tap[4];
  tap[3] = *(const uint4*)base;
  if (t >= 1) tap[2] = *(const uint4*)(base - 1*2*DIN_);
  if (t >= 2) tap[1] = *(const uint4*)(base - 2*2*DIN_);
  if (t >= 3) tap[0] = *(const uint4*)(base - 3*2*DIN_);
  float v[8];
  #pragma unroll
  for (int k = 0; k < 8; k++){
    float4 w = *(const float4*)(cw + (c8 + k)*4);
    float s = cb[c8 + k];
    #pragma unroll
    for (int j = 0; j < 4; j++){
      if (j >= 3 - t){
        const unsigned int* tp = (const unsigned int*)&tap[j];
        float xv = (k & 1) ? hi16(tp[k >> 1]) : lo16(tp[k >> 1]);
        s += xv * ((const float*)&w)[j];
      }
    }
    v[k] = s / (1.f + __expf(-s));
  }
  uint4 o;
  unsigned int* op = (unsigned int*)&o;
  #pragma unroll
  for (int k = 0; k < 4; k++)
    op[k] = (unsigned int)f2bf(v[2*k]) | ((unsigned int)f2bf(v[2*k+1]) << 16);
  *(uint4*)(xcb + (size_t)bt * DIN_ + c8) = o;
}

// ---------------- selective scan: 16 segments x 24 steps, 2-pass, 16 states/thread ----------------
// 256 blocks x 1024 threads (4 waves/SIMD); wave = time segment; chunks of 2 steps.
// Combine in two n-halves (h,P per half = 64 KB, overlaid on staging, barrier-separated).
#define WSTR2 896   /* floats per wave staging region */
__global__ __launch_bounds__(1024, 1) void scan_kernel(
    u16* __restrict__ ub_yb,
    const float* __restrict__ dbc, const u16* __restrict__ xz,
    const u16* __restrict__ dtp,
    const float* __restrict__ A_log, const float* __restrict__ Dp){
  __shared__ float smem[16384];   // 64 KB

  int tid = threadIdx.x;
  int lane = tid & 63;
  int seg  = tid >> 6;            // 0..15
  int b = blockIdx.x >> 4;
  int g = blockIdx.x & 15;
  int d = g*64 + lane;
  size_t base = (size_t)b * L_;

  float* wbase = smem + seg * WSTR2;
  float* sbc = wbase;             // [2][2][32]
  float* su  = wbase + 128;       // [2][2][64]
  float* sz  = wbase + 384;
  float* sdt = wbase + 640;

  int st = lane >> 5;             // staging step 0..1
  int j  = lane & 31;

  float A[16];
  #pragma unroll
  for (int n = 0; n < 16; n += 4){
    float4 av = *(const float4*)(A_log + (size_t)d*N_ + n);
    A[n] = -__expf(av.x); A[n+1] = -__expf(av.y); A[n+2] = -__expf(av.z); A[n+3] = -__expf(av.w);
  }
  float Dv = Dp[d];
  bool fastA = true;
  #pragma unroll
  for (int n = 0; n < 16; n++) fastA = fastA && (fabsf(A[n] + (float)(n+1)) < 1e-3f*(n+1));

  float h[16];
  #pragma unroll
  for (int n = 0; n < 16; n++) h[n] = 0.f;

  auto ldc = [&](int c, float& kbc, unsigned int& ku, unsigned int& kz,
                 unsigned int& kt, bool wz){
    size_t tokr = base + seg*SEGL + c*SC2 + st;
    kbc = dbc[tokr*64 + 32 + j];
    ku  = ((const unsigned int*)(ub_yb + tokr*DIN_ + g*64))[j];
    kt  = ((const unsigned int*)(dtp + tokr*DIN_ + g*64))[j];
    if (wz) kz = ((const unsigned int*)(xz + tokr*(2*DIN_) + DIN_ + g*64))[j];
  };
  auto stc = [&](int buf, float kbc, unsigned int ku, unsigned int kz,
                 unsigned int kt, bool wz){
    sbc[buf*64 + st*32 + j] = kbc;
    su [buf*128 + st*64 + 2*j]     = lo16(ku);
    su [buf*128 + st*64 + 2*j + 1] = hi16(ku);
    sdt[buf*128 + st*64 + 2*j]     = lo16(kt);
    sdt[buf*128 + st*64 + 2*j + 1] = hi16(kt);
    if (wz){
      sz[buf*128 + st*64 + 2*j]     = lo16(kz);
      sz[buf*128 + st*64 + 2*j + 1] = hi16(kz);
    }
  };

  // ================= PASS 1: local scan; S = sum(dt) =================
  float S = 0.f;
  {
    float kbc; unsigned int ku, kz, kt;
    ldc(0, kbc, ku, kz, kt, false);
    stc(0, kbc, ku, kz, kt, false);
    for (int c = 0; c < NCHK; c++){
      int cur = c & 1;
      bool have = (c + 1 < NCHK);
      float nbc; unsigned int nu, nz, nt;
      if (have) ldc(c+1, nbc, nu, nz, nt, false);
      for (int s = 0; s < SC2; s++){
        float dtv = sdt[cur*128 + s*64 + lane];
        float u   = su [cur*128 + s*64 + lane];
        const float* bcrow = sbc + cur*64 + s*32;
        float Bf[16];
        #pragma unroll
        for (int i = 0; i < 16; i += 4){
          float4 bv = *(const float4*)(bcrow + i);
          Bf[i] = bv.x; Bf[i+1] = bv.y; Bf[i+2] = bv.z; Bf[i+3] = bv.w;
        }
        float du = dtv * u;
        S += dtv;
        if (fastA){
          float q = __expf(-dtv);
          float p[16];
          qpowers(q, p);
          #pragma unroll
          for (int n = 0; n < 16; n++) h[n] = p[n] * h[n] + du * Bf[n];
        } else {
          #pragma unroll
          for (int n = 0; n < 16; n++){
            float dA = __expf(dtv * A[n]);
            h[n] = dA * h[n] + du * Bf[n];
          }
        }
      }
      if (have) stc(1 - cur, nbc, nu, nz, nt, false);
    }
  }

  // ================= combine, two n-halves =================
  #pragma unroll
  for (int half = 0; half < 2; half++){
    __syncthreads();
    #pragma unroll
    for (int n = 0; n < 8; n++){
      int nn = half*8 + n;
      smem[(n*NSEG + seg)*64 + lane]        = h[nn];
      smem[8192 + (n*NSEG + seg)*64 + lane] = __expf(A[nn] * S);
    }
    __syncthreads();
    float hs[8];
    #pragma unroll
    for (int n = 0; n < 8; n++) hs[n] = 0.f;
    for (int jj = 0; jj < seg; jj++){
      #pragma unroll
      for (int n = 0; n < 8; n++){
        float qh = smem[(n*NSEG + jj)*64 + lane];
        float qP = smem[8192 + (n*NSEG + jj)*64 + lane];
        hs[n] = qh + qP * hs[n];
      }
    }
    #pragma unroll
    for (int n = 0; n < 8; n++) h[half*8 + n] = hs[n];
  }
  __syncthreads();

  // ================= PASS 2: rescan with true h_start, write y =================
  {
    float kbc; unsigned int ku, kz, kt;
    ldc(0, kbc, ku, kz, kt, true);
    stc(0, kbc, ku, kz, kt, true);
    for (int c = 0; c < NCHK; c++){
      int cur = c & 1;
      bool have = (c + 1 < NCHK);
      float nbc; unsigned int nu, nz, nt;
      if (have) ldc(c+1, nbc, nu, nz, nt, true);
      for (int s = 0; s < SC2; s++){
        float dtv = sdt[cur*128 + s*64 + lane];
        float u   = su [cur*128 + s*64 + lane];
        float z   = sz [cur*128 + s*64 + lane];
        const float* bcrow = sbc + cur*64 + s*32;
        float Bf[16], Cf[16];
        #pragma unroll
        for (int i = 0; i < 16; i += 4){
          float4 bv = *(const float4*)(bcrow + i);
          float4 cv = *(const float4*)(bcrow + 16 + i);
          Bf[i] = bv.x; Bf[i+1] = bv.y; Bf[i+2] = bv.z; Bf[i+3] = bv.w;
          Cf[i] = cv.x; Cf[i+1] = cv.y; Cf[i+2] = cv.z; Cf[i+3] = cv.w;
        }
        float du = dtv * u;
        float acc = 0.f;
        if (fastA){
          float q = __expf(-dtv);
          float p[16];
          qpowers(q, p);
          #pragma unroll
          for (int n = 0; n < 16; n++){
            h[n] = p[n] * h[n] + du * Bf[n];
            acc += h[n] * Cf[n];
          }
        } else {
          #pragma unroll
          for (int n = 0; n < 16; n++){
            float dA = __expf(dtv * A[n]);
            h[n] = dA * h[n] + du * Bf[n];
            acc += h[n] * Cf[n];
          }
        }
        float y = acc + u * Dv;
        size_t tok = base + seg*SEGL + c*SC2 + s;
        ub_yb[tok*DIN_ + d] = f2bf(y * (z / (1.f + __expf(-z))));
      }
      if (have) stc(1 - cur, nbc, nu, nz, nt, true);
    }
  }
}

// ---------------- final LN + 512->7 head + de-normalize, wave per token ----------------
__global__ __launch_bounds__(256) void head_kernel(const float* __restrict__ x,
    const float* __restrict__ fw, const float* __restrict__ fb, const float* __restrict__ ow,
    const float* __restrict__ meanv, const float* __restrict__ stdv, void* __restrict__ out,
    const u16* __restrict__ dtype_probe){
  int wav = blockIdx.x*4 + (threadIdx.x >> 6);
  int lane = threadIdx.x & 63;
  if (wav >= B_*PRED_) return;
  int b = wav / PRED_;
  int tt = wav % PRED_;
  int tok = b*L_ + LBL_ + tt;
  const float* xr = x + (size_t)tok*DM_ + lane*8;
  float4 a = *(const float4*)xr;
  float4 bq = *(const float4*)(xr + 4);
  float v[8] = {a.x,a.y,a.z,a.w,bq.x,bq.y,bq.z,bq.w};
  float s = (v[0]+v[1])+(v[2]+v[3])+((v[4]+v[5])+(v[6]+v[7]));
  float mean = wredsum(s) * (1.f/DM_);
  float s2 = 0.f;
  #pragma unroll
  for (int j = 0; j < 8; j++){ v[j] -= mean; s2 += v[j]*v[j]; }
  float rstd = rsqrtf(wredsum(s2) * (1.f/DM_) + EPSF);
  const float* fwr = fw + lane*8;
  const float* fbr = fb + lane*8;
  #pragma unroll
  for (int j = 0; j < 8; j++) v[j] = v[j] * rstd * fwr[j] + fbr[j];
  int isbf = (dtype_probe[0] == 0x3F80u);
  for (int o = 0; o < CIN_; o++){
    const float* owr = ow + (size_t)o*DM_ + lane*8;
    float part = 0.f;
    #pragma unroll
    for (int j = 0; j < 8; j++) part += v[j] * owr[j];
    part = wredsum(part);
    if (lane == 0){
      float res = part * stdv[b*CIN_ + o] + meanv[b*CIN_ + o];
      size_t oidx = (size_t)(b*PRED_ + tt)*CIN_ + o;
      if (isbf) ((u16*)out)[oidx] = f2bf(res);
      else      ((float*)out)[oidx] = res;
    }
  }
}

extern "C" void kernel_launch(void* const* d_in, const int* in_sizes, int n_in,
                              void* d_out, int out_size, void* d_ws, size_t ws_size,
                              hipStream_t stream){
  float* P = (float*)d_ws;

  Ptrs ps;
  for (int i = 0; i < 18; i++) ps.p[i] = d_in[2 + i];

  float* x    = P + A_X;
  u16*   lnxb = (u16*)(P + A_LNB);
  u16*   xcb  = (u16*)(P + A_LNB);
  u16*   xz   = (u16*)(P + A_XZ);
  u16*   dt   = (u16*)(P + A_DT);
  u16*   dtrb = (u16*)(P + A_DTR);
  float* dbc  = P + A_DBC;
  float* xd   = P + A_XD;
  float* meanv= P + A_MEAN;
  float* stdv = P + A_STD;
  const u16* bwi = (const u16*)(P + PO_INW);
  const u16* bwx = (const u16*)(P + PO_XPROJ);
  const u16* bwd = (const u16*)(P + PO_DTW);
  const u16* bwo = (const u16*)(P + PO_OUTW);

  convert_kernel<<<(P_TOTAL+255)/256, 256, 0, stream>>>(ps, P);
  prep_kernel<<<B_*CIN_, 64, 0, stream>>>(P + PO_XDEC, xd, meanv, stdv);
  embed_ln_kernel<<<(B_*L_)/4, 256, 0, stream>>>(
      xd, P + PO_TOKW, P + PO_XMARK, P + PO_TIMEF,
      P + PO_NORMW, P + PO_NORMB, x, lnxb);

  for (int e = 0; e < E_; e++){
    if (e > 0)
      ln_kernel<<<(B_*L_)/4, 256, 0, stream>>>(x, P + PO_NORMW + e*DM_, P + PO_NORMB + e*DM_, lnxb);
    gemm_mfma<128,0,1,0><<<dim3((2*DIN_)/128, (B_*L_)/128), 256, 0, stream>>>(
        lnxb, bwi + (size_t)e*2*DIN_*DM_, xz, B_*L_, 2*DIN_, DM_, nullptr);
    conv_silu_kernel<<<(B_*L_*DIN_)/(256*8), 256, 0, stream>>>(
        xz, P + PO_CONVW + e*DIN_*DCONV_, P + PO_CONVB + e*DIN_, xcb);
    gemm_mfma<64,0,0,1><<<dim3(1, (B_*L_)/128), 256, 0, stream>>>(
        xcb, bwx + (size_t)e*64*DIN_, dbc, B_*L_, 64, DIN_, dtrb);
    dtproj_mfma<<<dim3(DIN_/64, (B_*L_)/128), 256, 0, stream>>>(
        dtrb, bwd + (size_t)e*DIN_*DTR_, P + PO_DTB + e*DIN_, dt);
    scan_kernel<<<256, 1024, 0, stream>>>(
        xcb, dbc, xz, dt, P + PO_ALOG + e*DIN_*N_, P + PO_DP + e*DIN_);
    gemm_mfma<64,1,0,0><<<dim3(DM_/64, (B_*L_)/128), 256, 0, stream>>>(
        xcb, bwo + (size_t)e*DM_*DIN_, x, B_*L_, DM_, DIN_, nullptr);
  }

  head_kernel<<<(B_*PRED_+3)/4, 256, 0, stream>>>(
      x, P + PO_FNW, P + PO_FNB, P + PO_HEADW, meanv, stdv, d_out, (const u16*)d_in[6]);
}